// Round 1
// baseline (643.321 us; speedup 1.0000x reference)
//
#include <hip/hip_runtime.h>
#include <float.h>

#define LRELU_SLOPE 0.2f

__device__ __forceinline__ float lrelu(float x) { return x >= 0.0f ? x : LRELU_SLOPE * x; }

__device__ __forceinline__ float sel4(float a, float b, float c, float d, int h) {
  float r = a;
  r = (h == 1) ? b : r;
  r = (h == 2) ? c : r;
  r = (h == 3) ? d : r;
  return r;
}

// ---------------- CSR build ----------------

__global__ void k_hist(const int* __restrict__ ei, int E, int* __restrict__ deg) {
  int e = blockIdx.x * blockDim.x + threadIdx.x;
  if (e < E) atomicAdd(&deg[ei[E + e]], 1);
}

__global__ __launch_bounds__(1024) void k_scan(const int* __restrict__ deg,
                                               int* __restrict__ rowptr,
                                               int* __restrict__ fill, int n) {
  __shared__ int part[1024];
  int tid = threadIdx.x;
  int chunk = (n + 1023) / 1024;
  int beg = tid * chunk; if (beg > n) beg = n;
  int end = beg + chunk; if (end > n) end = n;
  int s = 0;
  for (int i = beg; i < end; ++i) s += deg[i];
  part[tid] = s;
  __syncthreads();
  for (int off = 1; off < 1024; off <<= 1) {
    int v = part[tid];
    int u = (tid >= off) ? part[tid - off] : 0;
    __syncthreads();
    part[tid] = v + u;
    __syncthreads();
  }
  int run = (tid > 0) ? part[tid - 1] : 0;
  for (int i = beg; i < end; ++i) { rowptr[i] = run; fill[i] = run; run += deg[i]; }
  if (tid == 0) rowptr[n] = part[1023];
}

__global__ void k_scatter(const int* __restrict__ ei, int E, int* __restrict__ fill,
                          int* __restrict__ colx) {
  int e = blockIdx.x * blockDim.x + threadIdx.x;
  if (e < E) {
    int s = ei[e], d = ei[E + e];
    int p = atomicAdd(&fill[d], 1);
    colx[p] = s;
  }
}

// ---------------- GEMM 128->128 + attention logits (fused epilogue) ----------------
// One wave handles 4 rows; W (128x128, 64KB) in LDS; lane owns output cols 2*lane, 2*lane+1.

__global__ __launch_bounds__(256) void gemm128_att(
    const float* __restrict__ x, const float* __restrict__ W,
    const float* __restrict__ a_s, const float* __restrict__ a_d,
    float* __restrict__ h, float* __restrict__ als, float* __restrict__ ald, int n) {
  __shared__ float Ws[128 * 128];
  __shared__ float xs[4][4][128];
  int tid = threadIdx.x;
  for (int i = tid * 4; i < 128 * 128; i += 1024)
    *(float4*)&Ws[i] = *(const float4*)&W[i];
  __syncthreads();
  int w = tid >> 6, lane = tid & 63;
  int c0 = 2 * lane;
  float as0 = a_s[c0], as1 = a_s[c0 + 1];
  float ad0 = a_d[c0], ad1 = a_d[c0 + 1];
  int gw = blockIdx.x * 4 + w, nw = gridDim.x * 4;
  int nquads = (n + 3) >> 2;
  for (int q = gw; q < nquads; q += nw) {
    int r0 = q * 4;
#pragma unroll
    for (int j = 0; j < 4; ++j) {
      int r = r0 + j;
      if (r < n) {
        xs[w][j][lane] = x[(size_t)r * 128 + lane];
        xs[w][j][lane + 64] = x[(size_t)r * 128 + 64 + lane];
      } else {
        xs[w][j][lane] = 0.f;
        xs[w][j][lane + 64] = 0.f;
      }
    }
    float acc[4][2] = {};
#pragma unroll 16
    for (int k = 0; k < 128; ++k) {
      float2 wv = *(const float2*)&Ws[k * 128 + c0];
#pragma unroll
      for (int j = 0; j < 4; ++j) {
        float xv = xs[w][j][k];
        acc[j][0] = fmaf(xv, wv.x, acc[j][0]);
        acc[j][1] = fmaf(xv, wv.y, acc[j][1]);
      }
    }
#pragma unroll
    for (int j = 0; j < 4; ++j) {
      int r = r0 + j;
      if (r >= n) break;
      *(float2*)&h[(size_t)r * 128 + c0] = make_float2(acc[j][0], acc[j][1]);
      float ps = acc[j][0] * as0 + acc[j][1] * as1;
      float pd = acc[j][0] * ad0 + acc[j][1] * ad1;
#pragma unroll
      for (int off = 1; off < 16; off <<= 1) {
        ps += __shfl_xor(ps, off);
        pd += __shfl_xor(pd, off);
      }
      if ((lane & 15) == 0) {
        als[r * 4 + (lane >> 4)] = ps;
        ald[r * 4 + (lane >> 4)] = pd;
      }
    }
  }
}

// ---------------- GEMM 128->32 + attention logits (layer 3, heads=1) ----------------
// One wave handles 2 rows (lanes 0-31 row r, lanes 32-63 row r+1).

__global__ __launch_bounds__(256) void gemm32_att(
    const float* __restrict__ x, const float* __restrict__ W,
    const float* __restrict__ a_s, const float* __restrict__ a_d,
    float* __restrict__ h, float* __restrict__ als, float* __restrict__ ald, int n) {
  __shared__ float Ws[128 * 32];
  __shared__ float xs[4][2][128];
  int tid = threadIdx.x;
  for (int i = tid * 4; i < 128 * 32; i += 1024)
    *(float4*)&Ws[i] = *(const float4*)&W[i];
  __syncthreads();
  int w = tid >> 6, lane = tid & 63;
  int half = lane >> 5, c = lane & 31;
  float asv = a_s[c], adv = a_d[c];
  int gw = blockIdx.x * 4 + w, nw = gridDim.x * 4;
  int npairs = (n + 1) >> 1;
  for (int p = gw; p < npairs; p += nw) {
    int row = p * 2 + half;
    bool valid = row < n;
    if (valid) {
#pragma unroll
      for (int j = 0; j < 4; ++j)
        xs[w][half][c + 32 * j] = x[(size_t)row * 128 + c + 32 * j];
    }
    float acc = 0.f;
#pragma unroll 16
    for (int k = 0; k < 128; ++k)
      acc = fmaf(xs[w][half][k], Ws[k * 32 + c], acc);
    float ps = acc * asv, pd = acc * adv;
#pragma unroll
    for (int off = 1; off < 32; off <<= 1) {
      ps += __shfl_xor(ps, off);
      pd += __shfl_xor(pd, off);
    }
    if (valid) {
      h[(size_t)row * 32 + c] = acc;
      if (c == 0) { als[row] = ps; ald[row] = pd; }
    }
  }
}

// ---------------- Aggregation, layers 1/2 (H=4, C=32, concat) ----------------
// One wave per node. Phase 1: segment max (edge-parallel). Phase 2: segment sum.
// Phase 3: sequential edges, lane owns channels 2*lane, 2*lane+1 (head = lane>>4).
// Self-loop handled analytically.

__global__ __launch_bounds__(256) void k_agg128(
    const float* __restrict__ h, const float* __restrict__ als,
    const float* __restrict__ ald, const int* __restrict__ rowptr,
    const int* __restrict__ colx, const float* __restrict__ bias,
    float* __restrict__ out, int n, int do_elu) {
  int w = threadIdx.x >> 6, lane = threadIdx.x & 63;
  int node = blockIdx.x * 4 + w;
  if (node >= n) return;
  int beg = rowptr[node], end = rowptr[node + 1];
  float4 ad = ((const float4*)ald)[node];
  float4 asl = ((const float4*)als)[node];
  float es0 = lrelu(asl.x + ad.x), es1 = lrelu(asl.y + ad.y);
  float es2 = lrelu(asl.z + ad.z), es3 = lrelu(asl.w + ad.w);
  float m0 = es0, m1 = es1, m2 = es2, m3 = es3;
  for (int i = beg + lane; i < end; i += 64) {
    float4 as = ((const float4*)als)[colx[i]];
    m0 = fmaxf(m0, lrelu(as.x + ad.x));
    m1 = fmaxf(m1, lrelu(as.y + ad.y));
    m2 = fmaxf(m2, lrelu(as.z + ad.z));
    m3 = fmaxf(m3, lrelu(as.w + ad.w));
  }
#pragma unroll
  for (int off = 1; off < 64; off <<= 1) {
    m0 = fmaxf(m0, __shfl_xor(m0, off));
    m1 = fmaxf(m1, __shfl_xor(m1, off));
    m2 = fmaxf(m2, __shfl_xor(m2, off));
    m3 = fmaxf(m3, __shfl_xor(m3, off));
  }
  float z0 = 0.f, z1 = 0.f, z2 = 0.f, z3 = 0.f;
  for (int i = beg + lane; i < end; i += 64) {
    float4 as = ((const float4*)als)[colx[i]];
    z0 += __expf(lrelu(as.x + ad.x) - m0);
    z1 += __expf(lrelu(as.y + ad.y) - m1);
    z2 += __expf(lrelu(as.z + ad.z) - m2);
    z3 += __expf(lrelu(as.w + ad.w) - m3);
  }
  if (lane == 0) {
    z0 += __expf(es0 - m0); z1 += __expf(es1 - m1);
    z2 += __expf(es2 - m2); z3 += __expf(es3 - m3);
  }
#pragma unroll
  for (int off = 1; off < 64; off <<= 1) {
    z0 += __shfl_xor(z0, off);
    z1 += __shfl_xor(z1, off);
    z2 += __shfl_xor(z2, off);
    z3 += __shfl_xor(z3, off);
  }
  int head = lane >> 4;
  float mh = sel4(m0, m1, m2, m3, head);
  float invh = sel4(1.f / (z0 + 1e-16f), 1.f / (z1 + 1e-16f),
                    1.f / (z2 + 1e-16f), 1.f / (z3 + 1e-16f), head);
  float adh = sel4(ad.x, ad.y, ad.z, ad.w, head);
  int c0 = 2 * lane;
  float acc0 = 0.f, acc1 = 0.f;
  for (int i = beg; i < end; ++i) {
    int s = colx[i];
    float4 as = ((const float4*)als)[s];
    float ash = sel4(as.x, as.y, as.z, as.w, head);
    float alpha = __expf(lrelu(ash + adh) - mh) * invh;
    float2 hv = *(const float2*)&h[(size_t)s * 128 + c0];
    acc0 = fmaf(alpha, hv.x, acc0);
    acc1 = fmaf(alpha, hv.y, acc1);
  }
  {
    float ash = sel4(asl.x, asl.y, asl.z, asl.w, head);
    float alpha = __expf(lrelu(ash + adh) - mh) * invh;
    float2 hv = *(const float2*)&h[(size_t)node * 128 + c0];
    acc0 = fmaf(alpha, hv.x, acc0);
    acc1 = fmaf(alpha, hv.y, acc1);
  }
  float o0 = acc0 + bias[c0], o1 = acc1 + bias[c0 + 1];
  if (do_elu) {
    o0 = (o0 > 0.f) ? o0 : (__expf(o0) - 1.f);
    o1 = (o1 > 0.f) ? o1 : (__expf(o1) - 1.f);
  }
  *(float2*)&out[(size_t)node * 128 + c0] = make_float2(o0, o1);
}

// ---------------- Aggregation, layer 3 (H=1, C=32, mean==identity) ----------------

__global__ __launch_bounds__(256) void k_agg32(
    const float* __restrict__ h, const float* __restrict__ als,
    const float* __restrict__ ald, const int* __restrict__ rowptr,
    const int* __restrict__ colx, const float* __restrict__ bias,
    float* __restrict__ out, int n) {
  int w = threadIdx.x >> 6, lane = threadIdx.x & 63;
  int node = blockIdx.x * 4 + w;
  if (node >= n) return;
  int beg = rowptr[node], end = rowptr[node + 1];
  float ad = ald[node];
  float es = lrelu(als[node] + ad);
  float m = es;
  for (int i = beg + lane; i < end; i += 64) m = fmaxf(m, lrelu(als[colx[i]] + ad));
#pragma unroll
  for (int off = 1; off < 64; off <<= 1) m = fmaxf(m, __shfl_xor(m, off));
  float z = 0.f;
  for (int i = beg + lane; i < end; i += 64) z += __expf(lrelu(als[colx[i]] + ad) - m);
  if (lane == 0) z += __expf(es - m);
#pragma unroll
  for (int off = 1; off < 64; off <<= 1) z += __shfl_xor(z, off);
  float inv = 1.f / (z + 1e-16f);
  if (lane < 32) {
    float acc = 0.f;
    for (int i = beg; i < end; ++i) {
      int s = colx[i];
      float alpha = __expf(lrelu(als[s] + ad) - m) * inv;
      acc = fmaf(alpha, h[(size_t)s * 32 + lane], acc);
    }
    acc = fmaf(__expf(es - m) * inv, h[(size_t)node * 32 + lane], acc);
    out[(size_t)node * 32 + lane] = acc + bias[lane];
  }
}

// ---------------- launch ----------------

extern "C" void kernel_launch(void* const* d_in, const int* in_sizes, int n_in,
                              void* d_out, int out_size, void* d_ws, size_t ws_size,
                              hipStream_t stream) {
  const float* x   = (const float*)d_in[0];
  const int*   ei  = (const int*)d_in[1];
  const float* W1  = (const float*)d_in[4];
  const float* a1s = (const float*)d_in[5];
  const float* a1d = (const float*)d_in[6];
  const float* b1  = (const float*)d_in[7];
  const float* W2  = (const float*)d_in[8];
  const float* a2s = (const float*)d_in[9];
  const float* a2d = (const float*)d_in[10];
  const float* b2  = (const float*)d_in[11];
  const float* W3  = (const float*)d_in[12];
  const float* a3s = (const float*)d_in[13];
  const float* a3d = (const float*)d_in[14];
  const float* b3  = (const float*)d_in[15];
  const int N = in_sizes[0] / 128;
  const int E = in_sizes[1] / 2;

  char* ws = (char*)d_ws;
  size_t off = 0;
  auto alloc = [&](size_t bytes) -> void* {
    void* p = ws + off;
    off += (bytes + 255) & ~(size_t)255;
    return p;
  };
  float* h_a  = (float*)alloc((size_t)N * 128 * 4);
  float* h_b  = (float*)alloc((size_t)N * 128 * 4);
  float* als  = (float*)alloc((size_t)N * 4 * 4);
  float* ald  = (float*)alloc((size_t)N * 4 * 4);
  int* rowptr = (int*)alloc((size_t)(N + 1) * 4);
  int* deg    = (int*)alloc((size_t)N * 4);
  int* fill   = (int*)alloc((size_t)N * 4);
  int* colx   = (int*)alloc((size_t)E * 4);
  (void)ws_size; (void)n_in; (void)out_size;

  // CSR build (graph identical for all 3 layers)
  hipMemsetAsync(deg, 0, (size_t)N * 4, stream);
  k_hist<<<(E + 255) / 256, 256, 0, stream>>>(ei, E, deg);
  k_scan<<<1, 1024, 0, stream>>>(deg, rowptr, fill, N);
  k_scatter<<<(E + 255) / 256, 256, 0, stream>>>(ei, E, fill, colx);

  // Layer 1
  gemm128_att<<<512, 256, 0, stream>>>(x, W1, a1s, a1d, h_a, als, ald, N);
  k_agg128<<<(N + 3) / 4, 256, 0, stream>>>(h_a, als, ald, rowptr, colx, b1, h_b, N, 1);
  // Layer 2
  gemm128_att<<<512, 256, 0, stream>>>(h_b, W2, a2s, a2d, h_a, als, ald, N);
  k_agg128<<<(N + 3) / 4, 256, 0, stream>>>(h_a, als, ald, rowptr, colx, b2, h_b, N, 1);
  // Layer 3
  gemm32_att<<<256, 256, 0, stream>>>(h_b, W3, a3s, a3d, h_a, als, ald, N);
  k_agg32<<<(N + 3) / 4, 256, 0, stream>>>(h_a, als, ald, rowptr, colx, b3, (float*)d_out, N);
}

// Round 2
// 459.242 us; speedup vs baseline: 1.4008x; 1.4008x over previous
//
#include <hip/hip_runtime.h>
#include <hip/hip_fp16.h>

#define LRELU_SLOPE 0.2f

__device__ __forceinline__ float lrelu(float x) { return x >= 0.0f ? x : LRELU_SLOPE * x; }

__device__ __forceinline__ float sel4(float a, float b, float c, float d, int h) {
  float r = a;
  r = (h == 1) ? b : r;
  r = (h == 2) ? c : r;
  r = (h == 3) ? d : r;
  return r;
}

// ---------------- CSR build ----------------

__global__ void k_hist(const int* __restrict__ ei, int E, int* __restrict__ deg) {
  int e = blockIdx.x * blockDim.x + threadIdx.x;
  if (e < E) atomicAdd(&deg[ei[E + e]], 1);
}

__global__ __launch_bounds__(256) void k_scan1(const int* __restrict__ deg,
                                               int* __restrict__ rp,
                                               int* __restrict__ part, int n) {
  __shared__ int sm[256];
  int t = threadIdx.x;
  int i = blockIdx.x * 256 + t;
  int v = (i < n) ? deg[i] : 0;
  sm[t] = v;
  __syncthreads();
#pragma unroll
  for (int off = 1; off < 256; off <<= 1) {
    int u = (t >= off) ? sm[t - off] : 0;
    __syncthreads();
    sm[t] += u;
    __syncthreads();
  }
  if (i < n) rp[i] = sm[t] - v;  // exclusive within block
  if (t == 255) part[blockIdx.x] = sm[255];
}

__global__ __launch_bounds__(256) void k_scan2(int* __restrict__ part, int nb) {
  __shared__ int sm[256];
  int t = threadIdx.x;
  int v = (t < nb) ? part[t] : 0;
  sm[t] = v;
  __syncthreads();
#pragma unroll
  for (int off = 1; off < 256; off <<= 1) {
    int u = (t >= off) ? sm[t - off] : 0;
    __syncthreads();
    sm[t] += u;
    __syncthreads();
  }
  if (t < nb) part[t] = sm[t] - v;  // exclusive block offsets
}

__global__ __launch_bounds__(256) void k_scan3(int* __restrict__ rp, int* __restrict__ fill,
                                               const int* __restrict__ part, int n, int E) {
  int t = threadIdx.x;
  int i = blockIdx.x * 256 + t;
  if (i < n) {
    int v = rp[i] + part[blockIdx.x];
    rp[i] = v;
    fill[i] = v;
  }
  if (blockIdx.x == 0 && t == 0) rp[n] = E;
}

__global__ void k_scatter(const int* __restrict__ ei, int E, int* __restrict__ fill,
                          int* __restrict__ colx) {
  int e = blockIdx.x * blockDim.x + threadIdx.x;
  if (e < E) {
    int s = ei[e], d = ei[E + e];
    int p = atomicAdd(&fill[d], 1);
    colx[p] = s;
  }
}

// ---------------- GEMM 128->128 + attention logits, h stored fp16 ----------------
// 8 rows per wave; W (64KB) in LDS; lane owns cols 2*lane, 2*lane+1.
// xs read as float4 broadcasts (1 LDS b128 per row per 4 k's).

__global__ __launch_bounds__(256) void gemm128_att(
    const float* __restrict__ x, const float* __restrict__ W,
    const float* __restrict__ a_s, const float* __restrict__ a_d,
    __half* __restrict__ h, float* __restrict__ als, float* __restrict__ ald, int n) {
  __shared__ float Ws[128 * 128];
  __shared__ float xs[4][8][128];
  int tid = threadIdx.x;
  for (int i = tid * 4; i < 128 * 128; i += 1024)
    *(float4*)&Ws[i] = *(const float4*)&W[i];
  __syncthreads();
  int w = tid >> 6, lane = tid & 63;
  int c0 = 2 * lane;
  float as0 = a_s[c0], as1 = a_s[c0 + 1];
  float ad0 = a_d[c0], ad1 = a_d[c0 + 1];
  int gw = blockIdx.x * 4 + w, nw = gridDim.x * 4;
  int ngrp = (n + 7) >> 3;
  for (int g = gw; g < ngrp; g += nw) {
    int r0 = g * 8;
#pragma unroll
    for (int j = 0; j < 8; ++j) {
      int r = r0 + j;
      float2 v = (r < n) ? *(const float2*)&x[(size_t)r * 128 + c0] : make_float2(0.f, 0.f);
      *(float2*)&xs[w][j][c0] = v;
    }
    float acc[8][2] = {};
#pragma unroll 2
    for (int k0 = 0; k0 < 128; k0 += 4) {
      float4 xv[8];
#pragma unroll
      for (int j = 0; j < 8; ++j) xv[j] = *(const float4*)&xs[w][j][k0];
#pragma unroll
      for (int kk = 0; kk < 4; ++kk) {
        float2 wv = *(const float2*)&Ws[(k0 + kk) * 128 + c0];
#pragma unroll
        for (int j = 0; j < 8; ++j) {
          float xvj = (kk == 0) ? xv[j].x : (kk == 1) ? xv[j].y : (kk == 2) ? xv[j].z : xv[j].w;
          acc[j][0] = fmaf(xvj, wv.x, acc[j][0]);
          acc[j][1] = fmaf(xvj, wv.y, acc[j][1]);
        }
      }
    }
#pragma unroll
    for (int j = 0; j < 8; ++j) {
      int r = r0 + j;
      if (r >= n) break;
      *(__half2*)&h[(size_t)r * 128 + c0] = __float22half2_rn(make_float2(acc[j][0], acc[j][1]));
      float ps = acc[j][0] * as0 + acc[j][1] * as1;
      float pd = acc[j][0] * ad0 + acc[j][1] * ad1;
#pragma unroll
      for (int off = 1; off < 16; off <<= 1) {
        ps += __shfl_xor(ps, off);
        pd += __shfl_xor(pd, off);
      }
      if ((lane & 15) == 0) {
        als[r * 4 + (lane >> 4)] = ps;
        ald[r * 4 + (lane >> 4)] = pd;
      }
    }
  }
}

// ---------------- GEMM 128->32 + attention logits (layer 3, heads=1, h fp32) ----------------

__global__ __launch_bounds__(256) void gemm32_att(
    const float* __restrict__ x, const float* __restrict__ W,
    const float* __restrict__ a_s, const float* __restrict__ a_d,
    float* __restrict__ h, float* __restrict__ als, float* __restrict__ ald, int n) {
  __shared__ float Ws[128 * 32];
  __shared__ float xs[4][2][128];
  int tid = threadIdx.x;
  for (int i = tid * 4; i < 128 * 32; i += 1024)
    *(float4*)&Ws[i] = *(const float4*)&W[i];
  __syncthreads();
  int w = tid >> 6, lane = tid & 63;
  int half = lane >> 5, c = lane & 31;
  float asv = a_s[c], adv = a_d[c];
  int gw = blockIdx.x * 4 + w, nw = gridDim.x * 4;
  int npairs = (n + 1) >> 1;
  for (int p = gw; p < npairs; p += nw) {
    int row = p * 2 + half;
    bool valid = row < n;
    if (valid) {
#pragma unroll
      for (int j = 0; j < 4; ++j)
        xs[w][half][c + 32 * j] = x[(size_t)row * 128 + c + 32 * j];
    }
    float acc = 0.f;
#pragma unroll 16
    for (int k = 0; k < 128; ++k)
      acc = fmaf(xs[w][half][k], Ws[k * 32 + c], acc);
    float ps = acc * asv, pd = acc * adv;
#pragma unroll
    for (int off = 1; off < 32; off <<= 1) {
      ps += __shfl_xor(ps, off);
      pd += __shfl_xor(pd, off);
    }
    if (valid) {
      h[(size_t)row * 32 + c] = acc;
      if (c == 0) { als[row] = ps; ald[row] = pd; }
    }
  }
}

// ---------------- Aggregation, layers 1/2: single pass, no max-subtraction ----------------
// exp(e-m)/sum(exp(e-m)) == exp(e)/sum(exp(e)); |e| <~ 6 so fp32 exp is safe.
// One wave per node; lane owns channels 2*lane,2*lane+1; head = lane>>4.
// z is identical across the 16 lanes of a head group -> no reduce needed.

__global__ __launch_bounds__(256) void k_agg128(
    const __half* __restrict__ h, const float* __restrict__ als,
    const float* __restrict__ ald, const int* __restrict__ rowptr,
    const int* __restrict__ colx, const float* __restrict__ bias,
    float* __restrict__ out, int n, int do_elu) {
  int w = threadIdx.x >> 6, lane = threadIdx.x & 63;
  int node = blockIdx.x * 4 + w;
  if (node >= n) return;
  int beg = rowptr[node], end = rowptr[node + 1];
  float4 ad4 = ((const float4*)ald)[node];
  int head = lane >> 4;
  float adh = sel4(ad4.x, ad4.y, ad4.z, ad4.w, head);
  int c0 = 2 * lane;
  float z = 0.f, acc0 = 0.f, acc1 = 0.f;
  for (int i = beg; i < end; ++i) {
    int s = colx[i];
    float4 as4 = ((const float4*)als)[s];
    float ash = sel4(as4.x, as4.y, as4.z, as4.w, head);
    float wgt = __expf(lrelu(ash + adh));
    float2 hf = __half22float2(*(const __half2*)&h[(size_t)s * 128 + c0]);
    z += wgt;
    acc0 = fmaf(wgt, hf.x, acc0);
    acc1 = fmaf(wgt, hf.y, acc1);
  }
  {  // self loop
    float4 as4 = ((const float4*)als)[node];
    float ash = sel4(as4.x, as4.y, as4.z, as4.w, head);
    float wgt = __expf(lrelu(ash + adh));
    float2 hf = __half22float2(*(const __half2*)&h[(size_t)node * 128 + c0]);
    z += wgt;
    acc0 = fmaf(wgt, hf.x, acc0);
    acc1 = fmaf(wgt, hf.y, acc1);
  }
  float inv = 1.f / z;
  float o0 = acc0 * inv + bias[c0], o1 = acc1 * inv + bias[c0 + 1];
  if (do_elu) {
    o0 = (o0 > 0.f) ? o0 : (__expf(o0) - 1.f);
    o1 = (o1 > 0.f) ? o1 : (__expf(o1) - 1.f);
  }
  *(float2*)&out[(size_t)node * 128 + c0] = make_float2(o0, o1);
}

// ---------------- Aggregation, layer 3 (H=1, C=32): single pass, halves split edges ----------------

__global__ __launch_bounds__(256) void k_agg32(
    const float* __restrict__ h, const float* __restrict__ als,
    const float* __restrict__ ald, const int* __restrict__ rowptr,
    const int* __restrict__ colx, const float* __restrict__ bias,
    float* __restrict__ out, int n) {
  int w = threadIdx.x >> 6, lane = threadIdx.x & 63;
  int node = blockIdx.x * 4 + w;
  if (node >= n) return;
  int beg = rowptr[node], end = rowptr[node + 1];
  int half = lane >> 5, c = lane & 31;
  float ad = ald[node];
  float z = 0.f, acc = 0.f;
  for (int i = beg + half; i < end; i += 2) {
    int s = colx[i];
    float wgt = __expf(lrelu(als[s] + ad));
    z += wgt;
    acc = fmaf(wgt, h[(size_t)s * 32 + c], acc);
  }
  z += __shfl_xor(z, 32);
  acc += __shfl_xor(acc, 32);
  float wself = __expf(lrelu(als[node] + ad));
  z += wself;
  acc = fmaf(wself, h[(size_t)node * 32 + c], acc);
  if (half == 0) out[(size_t)node * 32 + c] = acc / z + bias[c];
}

// ---------------- launch ----------------

extern "C" void kernel_launch(void* const* d_in, const int* in_sizes, int n_in,
                              void* d_out, int out_size, void* d_ws, size_t ws_size,
                              hipStream_t stream) {
  const float* x   = (const float*)d_in[0];
  const int*   ei  = (const int*)d_in[1];
  const float* W1  = (const float*)d_in[4];
  const float* a1s = (const float*)d_in[5];
  const float* a1d = (const float*)d_in[6];
  const float* b1  = (const float*)d_in[7];
  const float* W2  = (const float*)d_in[8];
  const float* a2s = (const float*)d_in[9];
  const float* a2d = (const float*)d_in[10];
  const float* b2  = (const float*)d_in[11];
  const float* W3  = (const float*)d_in[12];
  const float* a3s = (const float*)d_in[13];
  const float* a3d = (const float*)d_in[14];
  const float* b3  = (const float*)d_in[15];
  const int N = in_sizes[0] / 128;
  const int E = in_sizes[1] / 2;

  char* ws = (char*)d_ws;
  size_t off = 0;
  auto alloc = [&](size_t bytes) -> void* {
    void* p = ws + off;
    off += (bytes + 255) & ~(size_t)255;
    return p;
  };
  float*  buf_f = (float*)alloc((size_t)N * 128 * 4);   // fp32 layer output
  __half* h_h   = (__half*)alloc((size_t)N * 128 * 2);  // fp16 pre-agg features
  float*  h32   = (float*)alloc((size_t)N * 32 * 4);    // layer-3 features (fp32)
  float*  als   = (float*)alloc((size_t)N * 4 * 4);
  float*  ald   = (float*)alloc((size_t)N * 4 * 4);
  float*  als1  = (float*)alloc((size_t)N * 4);
  float*  ald1  = (float*)alloc((size_t)N * 4);
  int* rowptr   = (int*)alloc((size_t)(N + 1) * 4);
  int* deg      = (int*)alloc((size_t)N * 4);
  int* fill     = (int*)alloc((size_t)N * 4);
  int* part     = (int*)alloc(256 * 4);
  int* colx     = (int*)alloc((size_t)E * 4);
  (void)ws_size; (void)n_in; (void)out_size;

  // CSR build (graph identical for all 3 layers)
  hipMemsetAsync(deg, 0, (size_t)N * 4, stream);
  k_hist<<<(E + 255) / 256, 256, 0, stream>>>(ei, E, deg);
  int nb = (N + 255) / 256;
  k_scan1<<<nb, 256, 0, stream>>>(deg, rowptr, part, N);
  k_scan2<<<1, 256, 0, stream>>>(part, nb);
  k_scan3<<<nb, 256, 0, stream>>>(rowptr, fill, part, N, E);
  k_scatter<<<(E + 255) / 256, 256, 0, stream>>>(ei, E, fill, colx);

  // Layer 1
  gemm128_att<<<512, 256, 0, stream>>>(x, W1, a1s, a1d, h_h, als, ald, N);
  k_agg128<<<(N + 3) / 4, 256, 0, stream>>>(h_h, als, ald, rowptr, colx, b1, buf_f, N, 1);
  // Layer 2
  gemm128_att<<<512, 256, 0, stream>>>(buf_f, W2, a2s, a2d, h_h, als, ald, N);
  k_agg128<<<(N + 3) / 4, 256, 0, stream>>>(h_h, als, ald, rowptr, colx, b2, buf_f, N, 1);
  // Layer 3
  gemm32_att<<<256, 256, 0, stream>>>(buf_f, W3, a3s, a3d, h32, als1, ald1, N);
  k_agg32<<<(N + 3) / 4, 256, 0, stream>>>(h32, als1, ald1, rowptr, colx, b3, (float*)d_out, N);
}

// Round 3
// 357.723 us; speedup vs baseline: 1.7984x; 1.2838x over previous
//
#include <hip/hip_runtime.h>
#include <hip/hip_fp16.h>

#define LRELU_SLOPE 0.2f

__device__ __forceinline__ float lrelu(float x) { return x >= 0.0f ? x : LRELU_SLOPE * x; }

__device__ __forceinline__ float sel4(float a, float b, float c, float d, int h) {
  float r = a;
  r = (h == 1) ? b : r;
  r = (h == 2) ? c : r;
  r = (h == 3) ? d : r;
  return r;
}

// ---------------- CSR build ----------------

__global__ void k_hist(const int* __restrict__ ei, int E, int* __restrict__ deg) {
  int e = blockIdx.x * blockDim.x + threadIdx.x;
  if (e < E) atomicAdd(&deg[ei[E + e]], 1);
}

__global__ __launch_bounds__(256) void k_scan1(const int* __restrict__ deg,
                                               int* __restrict__ rp,
                                               int* __restrict__ part, int n) {
  __shared__ int sm[256];
  int t = threadIdx.x;
  int i = blockIdx.x * 256 + t;
  int v = (i < n) ? deg[i] : 0;
  sm[t] = v;
  __syncthreads();
#pragma unroll
  for (int off = 1; off < 256; off <<= 1) {
    int u = (t >= off) ? sm[t - off] : 0;
    __syncthreads();
    sm[t] += u;
    __syncthreads();
  }
  if (i < n) rp[i] = sm[t] - v;
  if (t == 255) part[blockIdx.x] = sm[255];
}

__global__ __launch_bounds__(256) void k_scan2(int* __restrict__ part, int nb) {
  __shared__ int sm[256];
  int t = threadIdx.x;
  int v = (t < nb) ? part[t] : 0;
  sm[t] = v;
  __syncthreads();
#pragma unroll
  for (int off = 1; off < 256; off <<= 1) {
    int u = (t >= off) ? sm[t - off] : 0;
    __syncthreads();
    sm[t] += u;
    __syncthreads();
  }
  if (t < nb) part[t] = sm[t] - v;
}

__global__ __launch_bounds__(256) void k_scan3(int* __restrict__ rp, int* __restrict__ fill,
                                               const int* __restrict__ part, int n, int E) {
  int t = threadIdx.x;
  int i = blockIdx.x * 256 + t;
  if (i < n) {
    int v = rp[i] + part[blockIdx.x];
    rp[i] = v;
    fill[i] = v;
  }
  if (blockIdx.x == 0 && t == 0) rp[n] = E;
}

__global__ void k_scatter(const int* __restrict__ ei, int E, int* __restrict__ fill,
                          int* __restrict__ colx, int* __restrict__ dste) {
  int e = blockIdx.x * blockDim.x + threadIdx.x;
  if (e < E) {
    int s = ei[e], d = ei[E + e];
    int p = atomicAdd(&fill[d], 1);
    colx[p] = s;
    dste[p] = d;
  }
}

// ---------------- per-edge softmax weights (CSR order), layers 1/2 ----------------

__global__ void k_wgt4(const int* __restrict__ colx, const int* __restrict__ dste,
                       const float* __restrict__ als, const float* __restrict__ ald,
                       float* __restrict__ wgt, int E) {
  int p = blockIdx.x * blockDim.x + threadIdx.x;
  if (p >= E) return;
  int s = colx[p], d = dste[p];
  float4 a = ((const float4*)als)[s];
  float4 b = ((const float4*)ald)[d];
  float4 o;
  o.x = __expf(lrelu(a.x + b.x));
  o.y = __expf(lrelu(a.y + b.y));
  o.z = __expf(lrelu(a.z + b.z));
  o.w = __expf(lrelu(a.w + b.w));
  ((float4*)wgt)[p] = o;
}

__global__ void k_wgt1(const int* __restrict__ colx, const int* __restrict__ dste,
                       const float* __restrict__ als, const float* __restrict__ ald,
                       float* __restrict__ wgt, int E) {
  int p = blockIdx.x * blockDim.x + threadIdx.x;
  if (p >= E) return;
  wgt[p] = __expf(lrelu(als[colx[p]] + ald[dste[p]]));
}

// ---------------- GEMM 128->128 + attention logits, W f16 in LDS ----------------
// 8 rows per wave; LDS = 32KB (W f16) + 16KB (xs) -> 3 blocks/CU (12 waves/CU).

__global__ __launch_bounds__(256) void gemm128_att(
    const float* __restrict__ x, const float* __restrict__ W,
    const float* __restrict__ a_s, const float* __restrict__ a_d,
    __half* __restrict__ h, float* __restrict__ als, float* __restrict__ ald, int n) {
  __shared__ __half Wh[128 * 128];
  __shared__ float xs[4][8][128];
  int tid = threadIdx.x;
  for (int i = tid * 4; i < 128 * 128; i += 1024) {
    float4 v = *(const float4*)&W[i];
    __half2* dst = (__half2*)&Wh[i];
    dst[0] = __float22half2_rn(make_float2(v.x, v.y));
    dst[1] = __float22half2_rn(make_float2(v.z, v.w));
  }
  __syncthreads();
  int w = tid >> 6, lane = tid & 63;
  int c0 = 2 * lane;
  float as0 = a_s[c0], as1 = a_s[c0 + 1];
  float ad0 = a_d[c0], ad1 = a_d[c0 + 1];
  int gw = blockIdx.x * 4 + w, nw = gridDim.x * 4;
  int ngrp = (n + 7) >> 3;
  for (int g = gw; g < ngrp; g += nw) {
    int r0 = g * 8;
#pragma unroll
    for (int j = 0; j < 8; ++j) {
      int r = r0 + j;
      float2 v = (r < n) ? *(const float2*)&x[(size_t)r * 128 + c0] : make_float2(0.f, 0.f);
      *(float2*)&xs[w][j][c0] = v;
    }
    float acc[8][2] = {};
#pragma unroll 2
    for (int k0 = 0; k0 < 128; k0 += 4) {
      float2 wf[4];
#pragma unroll
      for (int kk = 0; kk < 4; ++kk)
        wf[kk] = __half22float2(*(const __half2*)&Wh[(k0 + kk) * 128 + c0]);
#pragma unroll
      for (int j = 0; j < 8; ++j) {
        float4 xv = *(const float4*)&xs[w][j][k0];
        acc[j][0] = fmaf(xv.x, wf[0].x, acc[j][0]);
        acc[j][1] = fmaf(xv.x, wf[0].y, acc[j][1]);
        acc[j][0] = fmaf(xv.y, wf[1].x, acc[j][0]);
        acc[j][1] = fmaf(xv.y, wf[1].y, acc[j][1]);
        acc[j][0] = fmaf(xv.z, wf[2].x, acc[j][0]);
        acc[j][1] = fmaf(xv.z, wf[2].y, acc[j][1]);
        acc[j][0] = fmaf(xv.w, wf[3].x, acc[j][0]);
        acc[j][1] = fmaf(xv.w, wf[3].y, acc[j][1]);
      }
    }
#pragma unroll
    for (int j = 0; j < 8; ++j) {
      int r = r0 + j;
      if (r >= n) break;
      *(__half2*)&h[(size_t)r * 128 + c0] = __float22half2_rn(make_float2(acc[j][0], acc[j][1]));
      float ps = acc[j][0] * as0 + acc[j][1] * as1;
      float pd = acc[j][0] * ad0 + acc[j][1] * ad1;
#pragma unroll
      for (int off = 1; off < 16; off <<= 1) {
        ps += __shfl_xor(ps, off);
        pd += __shfl_xor(pd, off);
      }
      if ((lane & 15) == 0) {
        als[r * 4 + (lane >> 4)] = ps;
        ald[r * 4 + (lane >> 4)] = pd;
      }
    }
  }
}

// ---------------- GEMM 128->32 + attention logits (layer 3, heads=1) ----------------
// W transposed in LDS with pad-133 so each lane reads float4 along k.

__global__ __launch_bounds__(256) void gemm32_att(
    const float* __restrict__ x, const float* __restrict__ W,
    const float* __restrict__ a_s, const float* __restrict__ a_d,
    float* __restrict__ h, float* __restrict__ als, float* __restrict__ ald, int n) {
  __shared__ float WsT[32 * 133];
  __shared__ float xs[4][2][128];
  int tid = threadIdx.x;
  for (int i = tid; i < 128 * 32; i += 256) {
    int k = i >> 5, c = i & 31;
    WsT[c * 133 + k] = W[i];
  }
  __syncthreads();
  int w = tid >> 6, lane = tid & 63;
  int half = lane >> 5, c = lane & 31;
  float asv = a_s[c], adv = a_d[c];
  int gw = blockIdx.x * 4 + w, nw = gridDim.x * 4;
  int npairs = (n + 1) >> 1;
  for (int p = gw; p < npairs; p += nw) {
    int row = p * 2 + half;
    bool valid = row < n;
    if (valid) {
#pragma unroll
      for (int j = 0; j < 4; ++j)
        xs[w][half][c + 32 * j] = x[(size_t)row * 128 + c + 32 * j];
    }
    float acc = 0.f;
#pragma unroll 4
    for (int k0 = 0; k0 < 128; k0 += 4) {
      float4 xv = *(const float4*)&xs[w][half][k0];
      float4 wv = *(const float4*)&WsT[c * 133 + k0];
      acc = fmaf(xv.x, wv.x, acc);
      acc = fmaf(xv.y, wv.y, acc);
      acc = fmaf(xv.z, wv.z, acc);
      acc = fmaf(xv.w, wv.w, acc);
    }
    float ps = acc * asv, pd = acc * adv;
#pragma unroll
    for (int off = 1; off < 32; off <<= 1) {
      ps += __shfl_xor(ps, off);
      pd += __shfl_xor(pd, off);
    }
    if (valid) {
      h[(size_t)row * 32 + c] = acc;
      if (c == 0) { als[row] = ps; ald[row] = pd; }
    }
  }
}

// ---------------- Aggregation, layers 1/2: 4 edge-groups x 16 lanes ----------------
// lane = (g,q): g=lane>>4 edge group, q=lane&15 owns channels 8q..8q+7 (head=q>>2).
// Weights precomputed (CSR order). Reduce over g via shfl_xor(16,32).

__global__ __launch_bounds__(256) void k_agg128(
    const __half* __restrict__ h, const float* __restrict__ als,
    const float* __restrict__ ald, const int* __restrict__ rowptr,
    const int* __restrict__ colx, const float* __restrict__ wgt,
    const float* __restrict__ bias, float* __restrict__ out, int n, int do_elu) {
  int w = threadIdx.x >> 6, lane = threadIdx.x & 63;
  int node = blockIdx.x * 4 + w;
  if (node >= n) return;
  int g = lane >> 4, q = lane & 15, head = q >> 2;
  int beg = rowptr[node], end = rowptr[node + 1];
  float acc[8] = {};
  float z = 0.f;
  if (g == 0) {  // self loop
    float4 a4 = ((const float4*)als)[node];
    float4 d4 = ((const float4*)ald)[node];
    float ws = __expf(lrelu(sel4(a4.x, a4.y, a4.z, a4.w, head) +
                            sel4(d4.x, d4.y, d4.z, d4.w, head)));
    z = ws;
    float4 raw = *(const float4*)(h + (size_t)node * 128 + q * 8);
    const __half2* hh = (const __half2*)&raw;
#pragma unroll
    for (int j = 0; j < 4; ++j) {
      float2 f = __half22float2(hh[j]);
      acc[2 * j] = ws * f.x;
      acc[2 * j + 1] = ws * f.y;
    }
  }
  for (int i = beg; i < end; i += 4) {
    int e = i + g;
    if (e < end) {
      int s = colx[e];
      float wv = wgt[e * 4 + head];
      float4 raw = *(const float4*)(h + (size_t)s * 128 + q * 8);
      const __half2* hh = (const __half2*)&raw;
      z += wv;
#pragma unroll
      for (int j = 0; j < 4; ++j) {
        float2 f = __half22float2(hh[j]);
        acc[2 * j] = fmaf(wv, f.x, acc[2 * j]);
        acc[2 * j + 1] = fmaf(wv, f.y, acc[2 * j + 1]);
      }
    }
  }
#pragma unroll
  for (int off = 16; off <= 32; off <<= 1) {
    z += __shfl_xor(z, off);
#pragma unroll
    for (int j = 0; j < 8; ++j) acc[j] += __shfl_xor(acc[j], off);
  }
  if (g == 0) {
    float inv = 1.f / z;
    int c0 = q * 8;
    float o[8];
#pragma unroll
    for (int j = 0; j < 8; ++j) {
      float v = acc[j] * inv + bias[c0 + j];
      if (do_elu) v = (v > 0.f) ? v : (__expf(v) - 1.f);
      o[j] = v;
    }
    *(float4*)&out[(size_t)node * 128 + c0] = make_float4(o[0], o[1], o[2], o[3]);
    *(float4*)&out[(size_t)node * 128 + c0 + 4] = make_float4(o[4], o[5], o[6], o[7]);
  }
}

// ---------------- Aggregation, layer 3: 4 edge-groups x 16 lanes x 2ch ----------------

__global__ __launch_bounds__(256) void k_agg32(
    const float* __restrict__ h, const float* __restrict__ als,
    const float* __restrict__ ald, const int* __restrict__ rowptr,
    const int* __restrict__ colx, const float* __restrict__ wgt,
    const float* __restrict__ bias, float* __restrict__ out, int n) {
  int w = threadIdx.x >> 6, lane = threadIdx.x & 63;
  int node = blockIdx.x * 4 + w;
  if (node >= n) return;
  int g = lane >> 4, q = lane & 15;
  int beg = rowptr[node], end = rowptr[node + 1];
  float acc0 = 0.f, acc1 = 0.f, z = 0.f;
  if (g == 0) {
    float ws = __expf(lrelu(als[node] + ald[node]));
    float2 f = *(const float2*)&h[(size_t)node * 32 + 2 * q];
    z = ws;
    acc0 = ws * f.x;
    acc1 = ws * f.y;
  }
  for (int i = beg; i < end; i += 4) {
    int e = i + g;
    if (e < end) {
      int s = colx[e];
      float wv = wgt[e];
      float2 f = *(const float2*)&h[(size_t)s * 32 + 2 * q];
      z += wv;
      acc0 = fmaf(wv, f.x, acc0);
      acc1 = fmaf(wv, f.y, acc1);
    }
  }
#pragma unroll
  for (int off = 16; off <= 32; off <<= 1) {
    z += __shfl_xor(z, off);
    acc0 += __shfl_xor(acc0, off);
    acc1 += __shfl_xor(acc1, off);
  }
  if (g == 0) {
    float inv = 1.f / z;
    *(float2*)&out[(size_t)node * 32 + 2 * q] =
        make_float2(acc0 * inv + bias[2 * q], acc1 * inv + bias[2 * q + 1]);
  }
}

// ---------------- launch ----------------

extern "C" void kernel_launch(void* const* d_in, const int* in_sizes, int n_in,
                              void* d_out, int out_size, void* d_ws, size_t ws_size,
                              hipStream_t stream) {
  const float* x   = (const float*)d_in[0];
  const int*   ei  = (const int*)d_in[1];
  const float* W1  = (const float*)d_in[4];
  const float* a1s = (const float*)d_in[5];
  const float* a1d = (const float*)d_in[6];
  const float* b1  = (const float*)d_in[7];
  const float* W2  = (const float*)d_in[8];
  const float* a2s = (const float*)d_in[9];
  const float* a2d = (const float*)d_in[10];
  const float* b2  = (const float*)d_in[11];
  const float* W3  = (const float*)d_in[12];
  const float* a3s = (const float*)d_in[13];
  const float* a3d = (const float*)d_in[14];
  const float* b3  = (const float*)d_in[15];
  const int N = in_sizes[0] / 128;
  const int E = in_sizes[1] / 2;

  char* ws = (char*)d_ws;
  size_t off = 0;
  auto alloc = [&](size_t bytes) -> void* {
    void* p = ws + off;
    off += (bytes + 255) & ~(size_t)255;
    return p;
  };
  float*  buf_f = (float*)alloc((size_t)N * 128 * 4);   // fp32 layer output
  __half* h_h   = (__half*)alloc((size_t)N * 128 * 2);  // fp16 pre-agg features
  float*  h32   = (float*)alloc((size_t)N * 32 * 4);    // layer-3 features
  float*  als   = (float*)alloc((size_t)N * 4 * 4);
  float*  ald   = (float*)alloc((size_t)N * 4 * 4);
  float*  als1  = (float*)alloc((size_t)N * 4);
  float*  ald1  = (float*)alloc((size_t)N * 4);
  int* rowptr   = (int*)alloc((size_t)(N + 1) * 4);
  int* deg      = (int*)alloc((size_t)N * 4);
  int* fill     = (int*)alloc((size_t)N * 4);
  int* part     = (int*)alloc(256 * 4);
  int* colx     = (int*)alloc((size_t)E * 4);
  int* dste     = (int*)alloc((size_t)E * 4);
  float* wgt4   = (float*)alloc((size_t)E * 4 * 4);
  float* wgt1   = wgt4;  // layer-3 weights alias (wgt4 dead by then)
  (void)ws_size; (void)n_in; (void)out_size;

  // CSR build (graph identical for all 3 layers)
  hipMemsetAsync(deg, 0, (size_t)N * 4, stream);
  k_hist<<<(E + 255) / 256, 256, 0, stream>>>(ei, E, deg);
  int nb = (N + 255) / 256;
  k_scan1<<<nb, 256, 0, stream>>>(deg, rowptr, part, N);
  k_scan2<<<1, 256, 0, stream>>>(part, nb);
  k_scan3<<<nb, 256, 0, stream>>>(rowptr, fill, part, N, E);
  k_scatter<<<(E + 255) / 256, 256, 0, stream>>>(ei, E, fill, colx, dste);

  int ebl = (E + 255) / 256;
  // Layer 1
  gemm128_att<<<512, 256, 0, stream>>>(x, W1, a1s, a1d, h_h, als, ald, N);
  k_wgt4<<<ebl, 256, 0, stream>>>(colx, dste, als, ald, wgt4, E);
  k_agg128<<<(N + 3) / 4, 256, 0, stream>>>(h_h, als, ald, rowptr, colx, wgt4, b1, buf_f, N, 1);
  // Layer 2
  gemm128_att<<<512, 256, 0, stream>>>(buf_f, W2, a2s, a2d, h_h, als, ald, N);
  k_wgt4<<<ebl, 256, 0, stream>>>(colx, dste, als, ald, wgt4, E);
  k_agg128<<<(N + 3) / 4, 256, 0, stream>>>(h_h, als, ald, rowptr, colx, wgt4, b2, buf_f, N, 1);
  // Layer 3
  gemm32_att<<<256, 256, 0, stream>>>(buf_f, W3, a3s, a3d, h32, als1, ald1, N);
  k_wgt1<<<ebl, 256, 0, stream>>>(colx, dste, als1, ald1, wgt1, E);
  k_agg32<<<(N + 3) / 4, 256, 0, stream>>>(h32, als1, ald1, rowptr, colx, wgt1, b3, (float*)d_out, N);
}

// Round 4
// 298.029 us; speedup vs baseline: 2.1586x; 1.2003x over previous
//
#include <hip/hip_runtime.h>
#include <hip/hip_fp16.h>

#define LRELU_SLOPE 0.2f

typedef _Float16 f16x8 __attribute__((ext_vector_type(8)));
typedef float f32x4 __attribute__((ext_vector_type(4)));

__device__ __forceinline__ float lrelu(float x) { return x >= 0.0f ? x : LRELU_SLOPE * x; }

__device__ __forceinline__ float sel4(float a, float b, float c, float d, int h) {
  float r = a;
  r = (h == 1) ? b : r;
  r = (h == 2) ? c : r;
  r = (h == 3) ? d : r;
  return r;
}

// ---------------- CSR build ----------------

__global__ void k_hist(const int* __restrict__ dst, int E, int* __restrict__ deg) {
  int e = (blockIdx.x * blockDim.x + threadIdx.x) * 4;
  if (e + 3 < E) {
    int4 d = *(const int4*)&dst[e];
    atomicAdd(&deg[d.x], 1);
    atomicAdd(&deg[d.y], 1);
    atomicAdd(&deg[d.z], 1);
    atomicAdd(&deg[d.w], 1);
  } else {
    for (; e < E; ++e) atomicAdd(&deg[dst[e]], 1);
  }
}

__global__ __launch_bounds__(256) void k_scan1(const int* __restrict__ deg,
                                               int* __restrict__ rp,
                                               int* __restrict__ part, int n) {
  __shared__ int sm[256];
  int t = threadIdx.x;
  int i = blockIdx.x * 256 + t;
  int v = (i < n) ? deg[i] : 0;
  sm[t] = v;
  __syncthreads();
#pragma unroll
  for (int off = 1; off < 256; off <<= 1) {
    int u = (t >= off) ? sm[t - off] : 0;
    __syncthreads();
    sm[t] += u;
    __syncthreads();
  }
  if (i < n) rp[i] = sm[t] - v;
  if (t == 255) part[blockIdx.x] = sm[255];
}

__global__ __launch_bounds__(256) void k_scan2(int* __restrict__ part, int nb) {
  __shared__ int sm[256];
  int t = threadIdx.x;
  int v = (t < nb) ? part[t] : 0;
  sm[t] = v;
  __syncthreads();
#pragma unroll
  for (int off = 1; off < 256; off <<= 1) {
    int u = (t >= off) ? sm[t - off] : 0;
    __syncthreads();
    sm[t] += u;
    __syncthreads();
  }
  if (t < nb) part[t] = sm[t] - v;
}

__global__ __launch_bounds__(256) void k_scan3(int* __restrict__ rp, int* __restrict__ fill,
                                               const int* __restrict__ part, int n, int E) {
  int t = threadIdx.x;
  int i = blockIdx.x * 256 + t;
  if (i < n) {
    int v = rp[i] + part[blockIdx.x];
    rp[i] = v;
    fill[i] = v;
  }
  if (blockIdx.x == 0 && t == 0) rp[n] = E;
}

__global__ void k_scatter(const int* __restrict__ ei, int E, int* __restrict__ fill,
                          int2* __restrict__ edge2) {
  int e = blockIdx.x * blockDim.x + threadIdx.x;
  if (e < E) {
    int s = ei[e], d = ei[E + e];
    int p = atomicAdd(&fill[d], 1);
    edge2[p] = make_int2(s, d);
  }
}

// ---------------- W fragment prep (fp32 [K][N] row-major -> MFMA B-frag order, fp16) ----------------
// frag f = kt*NT + nt; lane l holds B[k = kt*32 + (l>>4)*8 + j][col = nt*16 + (l&15)], j=0..7.

__global__ void k_prepW(const float* __restrict__ W, __half* __restrict__ out, int NT) {
  int t = blockIdx.x * blockDim.x + threadIdx.x;
  int total = 4 * NT * 64;
  if (t >= total) return;
  int l = t & 63, f = t >> 6;
  int kt = f / NT, nt = f % NT;
  int k0 = kt * 32 + (l >> 4) * 8;
  int col = nt * 16 + (l & 15);
  union { __half h[8]; float4 v; } u;
#pragma unroll
  for (int j = 0; j < 8; ++j) u.h[j] = (__half)W[(size_t)(k0 + j) * (NT * 16) + col];
  *(float4*)(out + (size_t)t * 8) = u.v;
}

// ---------------- MFMA GEMM: [n x 128] x [128 x NT*16], fp16 inputs, fp32 accum ----------------
// One wave per 16-row tile. All W-frags in VGPRs. No LDS.

template <int NT, typename OUT>
__global__ __launch_bounds__(256, 2) void gemm_mfma(
    const float* __restrict__ x, const __half* __restrict__ wfrag,
    OUT* __restrict__ h, int n, int ntiles) {
  int lane = threadIdx.x & 63, w = threadIdx.x >> 6;
  const f16x8* wf = (const f16x8*)wfrag;
  f16x8 B[4][NT];
#pragma unroll
  for (int kt = 0; kt < 4; ++kt)
#pragma unroll
    for (int nt = 0; nt < NT; ++nt) B[kt][nt] = wf[(kt * NT + nt) * 64 + lane];
  int tile = blockIdx.x * 4 + w;
  if (tile >= ntiles) return;
  int r0 = tile * 16;
  int arow = r0 + (lane & 15);
  const float* xp = x + (size_t)arow * 128 + (lane >> 4) * 8;
  f16x8 A[4];
  bool full = (r0 + 16 <= n);
#pragma unroll
  for (int kt = 0; kt < 4; ++kt) {
    float4 lo, hi;
    if (full || arow < n) {
      lo = *(const float4*)(xp + kt * 32);
      hi = *(const float4*)(xp + kt * 32 + 4);
    } else {
      lo = make_float4(0.f, 0.f, 0.f, 0.f);
      hi = lo;
    }
    f16x8 a;
    a[0] = (_Float16)lo.x; a[1] = (_Float16)lo.y; a[2] = (_Float16)lo.z; a[3] = (_Float16)lo.w;
    a[4] = (_Float16)hi.x; a[5] = (_Float16)hi.y; a[6] = (_Float16)hi.z; a[7] = (_Float16)hi.w;
    A[kt] = a;
  }
  f32x4 acc[NT];
#pragma unroll
  for (int nt = 0; nt < NT; ++nt) acc[nt] = (f32x4){0.f, 0.f, 0.f, 0.f};
#pragma unroll
  for (int kt = 0; kt < 4; ++kt)
#pragma unroll
    for (int nt = 0; nt < NT; ++nt)
      acc[nt] = __builtin_amdgcn_mfma_f32_16x16x32_f16(A[kt], B[kt][nt], acc[nt], 0, 0, 0);
  int cb = lane & 15, rb = (lane >> 4) * 4;
#pragma unroll
  for (int nt = 0; nt < NT; ++nt)
#pragma unroll
    for (int r = 0; r < 4; ++r) {
      int row = r0 + rb + r;
      if (full || row < n) h[(size_t)row * (NT * 16) + nt * 16 + cb] = (OUT)acc[nt][r];
    }
}

// ---------------- attention logits from h ----------------
// layers 1/2: h fp16 [n][128]; wave handles 2 rows, lane owns 4 cols; head = (lane&31)>>3.

__global__ __launch_bounds__(256) void k_att4(
    const __half* __restrict__ h, const float* __restrict__ a_s,
    const float* __restrict__ a_d, float* __restrict__ als, float* __restrict__ ald, int n) {
  int w = threadIdx.x >> 6, lane = threadIdx.x & 63;
  int row = blockIdx.x * 8 + w * 2 + (lane >> 5);
  if (row >= n) return;
  int lr = lane & 31;
  int c0 = lr * 4;
  float4 as = *(const float4*)&a_s[c0];
  float4 ad = *(const float4*)&a_d[c0];
  float2 h01 = __half22float2(*(const __half2*)&h[(size_t)row * 128 + c0]);
  float2 h23 = __half22float2(*(const __half2*)&h[(size_t)row * 128 + c0 + 2]);
  float ps = h01.x * as.x + h01.y * as.y + h23.x * as.z + h23.y * as.w;
  float pd = h01.x * ad.x + h01.y * ad.y + h23.x * ad.z + h23.y * ad.w;
#pragma unroll
  for (int off = 1; off < 8; off <<= 1) {
    ps += __shfl_xor(ps, off);
    pd += __shfl_xor(pd, off);
  }
  if ((lr & 7) == 0) {
    int head = lr >> 3;
    als[row * 4 + head] = ps;
    ald[row * 4 + head] = pd;
  }
}

// layer 3: h fp32 [n][32], single head.
__global__ __launch_bounds__(256) void k_att1(
    const float* __restrict__ h, const float* __restrict__ a_s,
    const float* __restrict__ a_d, float* __restrict__ als, float* __restrict__ ald, int n) {
  int w = threadIdx.x >> 6, lane = threadIdx.x & 63;
  int row = blockIdx.x * 8 + w * 2 + (lane >> 5);
  if (row >= n) return;
  int lr = lane & 31;
  float hv = h[(size_t)row * 32 + lr];
  float ps = hv * a_s[lr], pd = hv * a_d[lr];
#pragma unroll
  for (int off = 1; off < 32; off <<= 1) {
    ps += __shfl_xor(ps, off);
    pd += __shfl_xor(pd, off);
  }
  if (lr == 0) { als[row] = ps; ald[row] = pd; }
}

// ---------------- per-edge softmax weights (CSR order) ----------------

__global__ void k_wgt4(const int2* __restrict__ edge2,
                       const float* __restrict__ als, const float* __restrict__ ald,
                       float* __restrict__ wgt, int E) {
  int p = blockIdx.x * blockDim.x + threadIdx.x;
  if (p >= E) return;
  int2 e2 = edge2[p];
  float4 a = ((const float4*)als)[e2.x];
  float4 b = ((const float4*)ald)[e2.y];
  float4 o;
  o.x = __expf(lrelu(a.x + b.x));
  o.y = __expf(lrelu(a.y + b.y));
  o.z = __expf(lrelu(a.z + b.z));
  o.w = __expf(lrelu(a.w + b.w));
  ((float4*)wgt)[p] = o;
}

__global__ void k_wgt1(const int2* __restrict__ edge2,
                       const float* __restrict__ als, const float* __restrict__ ald,
                       float* __restrict__ wgt, int E) {
  int p = blockIdx.x * blockDim.x + threadIdx.x;
  if (p >= E) return;
  int2 e2 = edge2[p];
  wgt[p] = __expf(lrelu(als[e2.x] + ald[e2.y]));
}

// ---------------- Aggregation, layers 1/2: 4 edge-groups x 16 lanes ----------------

__global__ __launch_bounds__(256) void k_agg128(
    const __half* __restrict__ h, const float* __restrict__ als,
    const float* __restrict__ ald, const int* __restrict__ rowptr,
    const int2* __restrict__ edge2, const float* __restrict__ wgt,
    const float* __restrict__ bias, float* __restrict__ out, int n, int do_elu) {
  int w = threadIdx.x >> 6, lane = threadIdx.x & 63;
  int node = blockIdx.x * 4 + w;
  if (node >= n) return;
  int g = lane >> 4, q = lane & 15, head = q >> 2;
  int beg = rowptr[node], end = rowptr[node + 1];
  float acc[8] = {};
  float z = 0.f;
  if (g == 0) {  // self loop
    float4 a4 = ((const float4*)als)[node];
    float4 d4 = ((const float4*)ald)[node];
    float ws = __expf(lrelu(sel4(a4.x, a4.y, a4.z, a4.w, head) +
                            sel4(d4.x, d4.y, d4.z, d4.w, head)));
    z = ws;
    float4 raw = *(const float4*)(h + (size_t)node * 128 + q * 8);
    const __half2* hh = (const __half2*)&raw;
#pragma unroll
    for (int j = 0; j < 4; ++j) {
      float2 f = __half22float2(hh[j]);
      acc[2 * j] = ws * f.x;
      acc[2 * j + 1] = ws * f.y;
    }
  }
  for (int i = beg; i < end; i += 4) {
    int e = i + g;
    if (e < end) {
      int s = edge2[e].x;
      float wv = wgt[e * 4 + head];
      float4 raw = *(const float4*)(h + (size_t)s * 128 + q * 8);
      const __half2* hh = (const __half2*)&raw;
      z += wv;
#pragma unroll
      for (int j = 0; j < 4; ++j) {
        float2 f = __half22float2(hh[j]);
        acc[2 * j] = fmaf(wv, f.x, acc[2 * j]);
        acc[2 * j + 1] = fmaf(wv, f.y, acc[2 * j + 1]);
      }
    }
  }
#pragma unroll
  for (int off = 16; off <= 32; off <<= 1) {
    z += __shfl_xor(z, off);
#pragma unroll
    for (int j = 0; j < 8; ++j) acc[j] += __shfl_xor(acc[j], off);
  }
  if (g == 0) {
    float inv = 1.f / z;
    int c0 = q * 8;
    float o[8];
#pragma unroll
    for (int j = 0; j < 8; ++j) {
      float v = acc[j] * inv + bias[c0 + j];
      if (do_elu) v = (v > 0.f) ? v : (__expf(v) - 1.f);
      o[j] = v;
    }
    *(float4*)&out[(size_t)node * 128 + c0] = make_float4(o[0], o[1], o[2], o[3]);
    *(float4*)&out[(size_t)node * 128 + c0 + 4] = make_float4(o[4], o[5], o[6], o[7]);
  }
}

// ---------------- Aggregation, layer 3 ----------------

__global__ __launch_bounds__(256) void k_agg32(
    const float* __restrict__ h, const float* __restrict__ als,
    const float* __restrict__ ald, const int* __restrict__ rowptr,
    const int2* __restrict__ edge2, const float* __restrict__ wgt,
    const float* __restrict__ bias, float* __restrict__ out, int n) {
  int w = threadIdx.x >> 6, lane = threadIdx.x & 63;
  int node = blockIdx.x * 4 + w;
  if (node >= n) return;
  int g = lane >> 4, q = lane & 15;
  int beg = rowptr[node], end = rowptr[node + 1];
  float acc0 = 0.f, acc1 = 0.f, z = 0.f;
  if (g == 0) {
    float ws = __expf(lrelu(als[node] + ald[node]));
    float2 f = *(const float2*)&h[(size_t)node * 32 + 2 * q];
    z = ws;
    acc0 = ws * f.x;
    acc1 = ws * f.y;
  }
  for (int i = beg; i < end; i += 4) {
    int e = i + g;
    if (e < end) {
      int s = edge2[e].x;
      float wv = wgt[e];
      float2 f = *(const float2*)&h[(size_t)s * 32 + 2 * q];
      z += wv;
      acc0 = fmaf(wv, f.x, acc0);
      acc1 = fmaf(wv, f.y, acc1);
    }
  }
#pragma unroll
  for (int off = 16; off <= 32; off <<= 1) {
    z += __shfl_xor(z, off);
    acc0 += __shfl_xor(acc0, off);
    acc1 += __shfl_xor(acc1, off);
  }
  if (g == 0) {
    float inv = 1.f / z;
    *(float2*)&out[(size_t)node * 32 + 2 * q] =
        make_float2(acc0 * inv + bias[2 * q], acc1 * inv + bias[2 * q + 1]);
  }
}

// ---------------- launch ----------------

extern "C" void kernel_launch(void* const* d_in, const int* in_sizes, int n_in,
                              void* d_out, int out_size, void* d_ws, size_t ws_size,
                              hipStream_t stream) {
  const float* x   = (const float*)d_in[0];
  const int*   ei  = (const int*)d_in[1];
  const float* W1  = (const float*)d_in[4];
  const float* a1s = (const float*)d_in[5];
  const float* a1d = (const float*)d_in[6];
  const float* b1  = (const float*)d_in[7];
  const float* W2  = (const float*)d_in[8];
  const float* a2s = (const float*)d_in[9];
  const float* a2d = (const float*)d_in[10];
  const float* b2  = (const float*)d_in[11];
  const float* W3  = (const float*)d_in[12];
  const float* a3s = (const float*)d_in[13];
  const float* a3d = (const float*)d_in[14];
  const float* b3  = (const float*)d_in[15];
  const int N = in_sizes[0] / 128;
  const int E = in_sizes[1] / 2;
  const int ntiles = (N + 15) / 16;

  char* ws = (char*)d_ws;
  size_t off = 0;
  auto alloc = [&](size_t bytes) -> void* {
    void* p = ws + off;
    off += (bytes + 255) & ~(size_t)255;
    return p;
  };
  float*  buf_f = (float*)alloc((size_t)N * 128 * 4);
  __half* h_h   = (__half*)alloc((size_t)N * 128 * 2);
  float*  h32   = (float*)alloc((size_t)N * 32 * 4);
  float*  als   = (float*)alloc((size_t)N * 4 * 4);
  float*  ald   = (float*)alloc((size_t)N * 4 * 4);
  float*  als1  = (float*)alloc((size_t)N * 4);
  float*  ald1  = (float*)alloc((size_t)N * 4);
  int* rowptr   = (int*)alloc((size_t)(N + 1) * 4);
  int* deg      = (int*)alloc((size_t)N * 4);
  int* fill     = (int*)alloc((size_t)N * 4);
  int* part     = (int*)alloc(256 * 4);
  int2* edge2   = (int2*)alloc((size_t)E * 8);
  float* wgt4   = (float*)alloc((size_t)E * 4 * 4);
  float* wgt1   = wgt4;
  __half* wf1   = (__half*)alloc(4 * 8 * 64 * 8 * 2);
  __half* wf2   = (__half*)alloc(4 * 8 * 64 * 8 * 2);
  __half* wf3   = (__half*)alloc(4 * 2 * 64 * 8 * 2);
  (void)ws_size; (void)n_in; (void)out_size;

  // CSR build
  hipMemsetAsync(deg, 0, (size_t)N * 4, stream);
  k_hist<<<(E / 4 + 255) / 256, 256, 0, stream>>>(ei + E, E, deg);
  int nb = (N + 255) / 256;
  k_scan1<<<nb, 256, 0, stream>>>(deg, rowptr, part, N);
  k_scan2<<<1, 256, 0, stream>>>(part, nb);
  k_scan3<<<nb, 256, 0, stream>>>(rowptr, fill, part, N, E);
  k_scatter<<<(E + 255) / 256, 256, 0, stream>>>(ei, E, fill, edge2);

  // W fragment prep
  k_prepW<<<8, 256, 0, stream>>>(W1, wf1, 8);
  k_prepW<<<8, 256, 0, stream>>>(W2, wf2, 8);
  k_prepW<<<2, 256, 0, stream>>>(W3, wf3, 2);

  int gblk = (ntiles + 3) / 4;
  int ebl = (E + 255) / 256;
  int rbl = (N + 7) / 8;
  // Layer 1
  gemm_mfma<8, __half><<<gblk, 256, 0, stream>>>(x, wf1, h_h, N, ntiles);
  k_att4<<<rbl, 256, 0, stream>>>(h_h, a1s, a1d, als, ald, N);
  k_wgt4<<<ebl, 256, 0, stream>>>(edge2, als, ald, wgt4, E);
  k_agg128<<<(N + 3) / 4, 256, 0, stream>>>(h_h, als, ald, rowptr, edge2, wgt4, b1, buf_f, N, 1);
  // Layer 2
  gemm_mfma<8, __half><<<gblk, 256, 0, stream>>>(buf_f, wf2, h_h, N, ntiles);
  k_att4<<<rbl, 256, 0, stream>>>(h_h, a2s, a2d, als, ald, N);
  k_wgt4<<<ebl, 256, 0, stream>>>(edge2, als, ald, wgt4, E);
  k_agg128<<<(N + 3) / 4, 256, 0, stream>>>(h_h, als, ald, rowptr, edge2, wgt4, b2, buf_f, N, 1);
  // Layer 3
  gemm_mfma<2, float><<<gblk, 256, 0, stream>>>(buf_f, wf3, h32, N, ntiles);
  k_att1<<<rbl, 256, 0, stream>>>(h32, a3s, a3d, als1, ald1, N);
  k_wgt1<<<ebl, 256, 0, stream>>>(edge2, als1, ald1, wgt1, E);
  k_agg32<<<(N + 3) / 4, 256, 0, stream>>>(h32, als1, ald1, rowptr, edge2, wgt1, b3, (float*)d_out, N);
}

// Round 5
// 269.059 us; speedup vs baseline: 2.3910x; 1.1077x over previous
//
#include <hip/hip_runtime.h>
#include <hip/hip_fp16.h>

#define LRELU_SLOPE 0.2f
#define NB 256
#define EPB 4096

typedef _Float16 f16x8 __attribute__((ext_vector_type(8)));
typedef float f32x4 __attribute__((ext_vector_type(4)));

__device__ __forceinline__ float lrelu(float x) { return x >= 0.0f ? x : LRELU_SLOPE * x; }

__device__ __forceinline__ float sel4(float a, float b, float c, float d, int h) {
  float r = a;
  r = (h == 1) ? b : r;
  r = (h == 2) ? c : r;
  r = (h == 3) ? d : r;
  return r;
}

// ---------------- CSR build ----------------

__global__ void k_hist(const int* __restrict__ dst, int E, int* __restrict__ deg) {
  int e = (blockIdx.x * blockDim.x + threadIdx.x) * 4;
  if (e + 3 < E) {
    int4 d = *(const int4*)&dst[e];
    atomicAdd(&deg[d.x], 1);
    atomicAdd(&deg[d.y], 1);
    atomicAdd(&deg[d.z], 1);
    atomicAdd(&deg[d.w], 1);
  } else {
    for (; e < E; ++e) atomicAdd(&deg[dst[e]], 1);
  }
}

__global__ __launch_bounds__(256) void k_scan1(const int* __restrict__ deg,
                                               int* __restrict__ rp,
                                               int* __restrict__ part, int n) {
  __shared__ int sm[256];
  int t = threadIdx.x;
  int i = blockIdx.x * 256 + t;
  int v = (i < n) ? deg[i] : 0;
  sm[t] = v;
  __syncthreads();
#pragma unroll
  for (int off = 1; off < 256; off <<= 1) {
    int u = (t >= off) ? sm[t - off] : 0;
    __syncthreads();
    sm[t] += u;
    __syncthreads();
  }
  if (i < n) rp[i] = sm[t] - v;
  if (t == 255) part[blockIdx.x] = sm[255];
}

__global__ __launch_bounds__(256) void k_scan2(int* __restrict__ part, int nb) {
  __shared__ int sm[256];
  int t = threadIdx.x;
  int v = (t < nb) ? part[t] : 0;
  sm[t] = v;
  __syncthreads();
#pragma unroll
  for (int off = 1; off < 256; off <<= 1) {
    int u = (t >= off) ? sm[t - off] : 0;
    __syncthreads();
    sm[t] += u;
    __syncthreads();
  }
  if (t < nb) part[t] = sm[t] - v;
}

__global__ __launch_bounds__(256) void k_scan3(int* __restrict__ rp,
                                               const int* __restrict__ part, int n, int E) {
  int t = threadIdx.x;
  int i = blockIdx.x * 256 + t;
  if (i < n) rp[i] += part[blockIdx.x];
  if (blockIdx.x == 0 && t == 0) rp[n] = E;
}

__global__ void k_initcur(const int* __restrict__ rowptr, int* __restrict__ gcur,
                          int stride, int n) {
  int t = threadIdx.x;
  if (t < NB) {
    int lo = t * stride;
    if (lo > n) lo = n;
    gcur[t] = rowptr[lo];
  }
}

// Phase 1: bucket edges by dst range; LDS reorder so global writes are grouped runs.
__global__ __launch_bounds__(256) void k_bucket(const int* __restrict__ ei, int E, int stride,
                                                int* __restrict__ gcur, int2* __restrict__ ebuck) {
  __shared__ int2 stage[EPB];
  __shared__ int addr[EPB];
  __shared__ int cnt[NB], offs[NB], gbase[NB], curl[NB], sm[NB];
  int t = threadIdx.x;
  int base = blockIdx.x * EPB;
  int count = E - base;
  if (count > EPB) count = EPB;
  if (count < 0) count = 0;
  cnt[t] = 0;
  __syncthreads();
  int2 er[16];
  int ne = 0;
#pragma unroll
  for (int k = 0; k < 16; ++k) {
    int i = k * 256 + t;
    if (i < count) {
      int e = base + i;
      er[k] = make_int2(ei[e], ei[E + e]);
      atomicAdd(&cnt[er[k].y / stride], 1);
      ne = k + 1;
    }
  }
  __syncthreads();
  sm[t] = cnt[t];
  __syncthreads();
#pragma unroll
  for (int off = 1; off < NB; off <<= 1) {
    int u = (t >= off) ? sm[t - off] : 0;
    __syncthreads();
    sm[t] += u;
    __syncthreads();
  }
  offs[t] = sm[t] - cnt[t];
  curl[t] = sm[t] - cnt[t];
  if (cnt[t] > 0) gbase[t] = atomicAdd(&gcur[t], cnt[t]);
  __syncthreads();
  for (int k = 0; k < ne; ++k) {
    int b = er[k].y / stride;
    int r = atomicAdd(&curl[b], 1);
    stage[r] = er[k];
    addr[r] = gbase[b] + (r - offs[b]);
  }
  __syncthreads();
  for (int i = t; i < count; i += 256) ebuck[addr[i]] = stage[i];
}

// Phase 2: per-bucket fine counting sort; node cursors in LDS, writes L2-local.
__global__ __launch_bounds__(256) void k_fine(const int2* __restrict__ ebuck,
                                              const int* __restrict__ rowptr,
                                              int* __restrict__ colx, int* __restrict__ dsts,
                                              int stride, int n) {
  __shared__ int cur[1024];
  int b = blockIdx.x;
  int lo = b * stride;
  if (lo > n) lo = n;
  int hi = lo + stride;
  if (hi > n) hi = n;
  int nn = hi - lo;
  int t = threadIdx.x;
  for (int j = t; j < nn; j += 256) cur[j] = rowptr[lo + j];
  __syncthreads();
  int ebeg = rowptr[lo], eend = rowptr[hi];
  for (int i = ebeg + t; i < eend; i += 256) {
    int2 e = ebuck[i];
    int p = atomicAdd(&cur[e.y - lo], 1);
    colx[p] = e.x;
    dsts[p] = e.y;
  }
}

// ---------------- W fragment prep (fp32 [K][N] -> MFMA B-frag order, fp16) ----------------

__global__ void k_prepW(const float* __restrict__ W, __half* __restrict__ out, int NT) {
  int t = blockIdx.x * blockDim.x + threadIdx.x;
  int total = 4 * NT * 64;
  if (t >= total) return;
  int l = t & 63, f = t >> 6;
  int kt = f / NT, nt = f % NT;
  int k0 = kt * 32 + (l >> 4) * 8;
  int col = nt * 16 + (l & 15);
  union { __half h[8]; float4 v; } u;
#pragma unroll
  for (int j = 0; j < 8; ++j) u.h[j] = (__half)W[(size_t)(k0 + j) * (NT * 16) + col];
  *(float4*)(out + (size_t)t * 8) = u.v;
}

// ---------------- MFMA GEMM + fused attention logits ----------------
// One wave per 16-row tile; all W-frags in VGPRs; no LDS.

template <int NT, int NH, typename OUT>
__global__ __launch_bounds__(256, 2) void gemm_mfma(
    const float* __restrict__ x, const __half* __restrict__ wfrag,
    const float* __restrict__ a_s, const float* __restrict__ a_d,
    OUT* __restrict__ h, float* __restrict__ als, float* __restrict__ ald,
    int n, int ntiles) {
  int lane = threadIdx.x & 63, w = threadIdx.x >> 6;
  const f16x8* wf = (const f16x8*)wfrag;
  f16x8 B[4][NT];
#pragma unroll
  for (int kt = 0; kt < 4; ++kt)
#pragma unroll
    for (int nt = 0; nt < NT; ++nt) B[kt][nt] = wf[(kt * NT + nt) * 64 + lane];
  int tile = blockIdx.x * 4 + w;
  if (tile >= ntiles) return;
  int r0 = tile * 16;
  int arow = r0 + (lane & 15);
  const float* xp = x + (size_t)arow * 128 + (lane >> 4) * 8;
  bool full = (r0 + 16 <= n);
  f16x8 A[4];
#pragma unroll
  for (int kt = 0; kt < 4; ++kt) {
    float4 lo, hi;
    if (full || arow < n) {
      lo = *(const float4*)(xp + kt * 32);
      hi = *(const float4*)(xp + kt * 32 + 4);
    } else {
      lo = make_float4(0.f, 0.f, 0.f, 0.f);
      hi = lo;
    }
    f16x8 a;
    a[0] = (_Float16)lo.x; a[1] = (_Float16)lo.y; a[2] = (_Float16)lo.z; a[3] = (_Float16)lo.w;
    a[4] = (_Float16)hi.x; a[5] = (_Float16)hi.y; a[6] = (_Float16)hi.z; a[7] = (_Float16)hi.w;
    A[kt] = a;
  }
  f32x4 acc[NT];
#pragma unroll
  for (int nt = 0; nt < NT; ++nt) acc[nt] = (f32x4){0.f, 0.f, 0.f, 0.f};
#pragma unroll
  for (int kt = 0; kt < 4; ++kt)
#pragma unroll
    for (int nt = 0; nt < NT; ++nt)
      acc[nt] = __builtin_amdgcn_mfma_f32_16x16x32_f16(A[kt], B[kt][nt], acc[nt], 0, 0, 0);
  int cb = lane & 15, rb = (lane >> 4) * 4;
  float asv[NT], adv[NT];
#pragma unroll
  for (int nt = 0; nt < NT; ++nt) {
    asv[nt] = a_s[nt * 16 + cb];
    adv[nt] = a_d[nt * 16 + cb];
  }
#pragma unroll
  for (int r = 0; r < 4; ++r) {
    int row = r0 + rb + r;
    if (!full && row >= n) break;
#pragma unroll
    for (int nt = 0; nt < NT; ++nt)
      h[(size_t)row * (NT * 16) + nt * 16 + cb] = (OUT)acc[nt][r];
    if (NH == 4) {
      float ps[4], pd[4];
#pragma unroll
      for (int hh = 0; hh < 4; ++hh) {
        ps[hh] = acc[2 * hh][r] * asv[2 * hh] + acc[2 * hh + 1][r] * asv[2 * hh + 1];
        pd[hh] = acc[2 * hh][r] * adv[2 * hh] + acc[2 * hh + 1][r] * adv[2 * hh + 1];
      }
#pragma unroll
      for (int off = 1; off < 16; off <<= 1) {
#pragma unroll
        for (int hh = 0; hh < 4; ++hh) {
          ps[hh] += __shfl_xor(ps[hh], off);
          pd[hh] += __shfl_xor(pd[hh], off);
        }
      }
      if (cb < 4) {
        als[row * 4 + cb] = sel4(ps[0], ps[1], ps[2], ps[3], cb);
        ald[row * 4 + cb] = sel4(pd[0], pd[1], pd[2], pd[3], cb);
      }
    } else {
      float ps = acc[0][r] * asv[0] + acc[1][r] * asv[1];
      float pd = acc[0][r] * adv[0] + acc[1][r] * adv[1];
#pragma unroll
      for (int off = 1; off < 16; off <<= 1) {
        ps += __shfl_xor(ps, off);
        pd += __shfl_xor(pd, off);
      }
      if (cb == 0) { als[row] = ps; ald[row] = pd; }
    }
  }
}

// ---------------- per-edge softmax weights (CSR order) ----------------

__global__ void k_wgt4(const int* __restrict__ colx, const int* __restrict__ dsts,
                       const float* __restrict__ als, const float* __restrict__ ald,
                       float* __restrict__ wgt, int E) {
  int p = blockIdx.x * blockDim.x + threadIdx.x;
  if (p >= E) return;
  float4 a = ((const float4*)als)[colx[p]];
  float4 b = ((const float4*)ald)[dsts[p]];
  float4 o;
  o.x = __expf(lrelu(a.x + b.x));
  o.y = __expf(lrelu(a.y + b.y));
  o.z = __expf(lrelu(a.z + b.z));
  o.w = __expf(lrelu(a.w + b.w));
  ((float4*)wgt)[p] = o;
}

__global__ void k_wgt1(const int* __restrict__ colx, const int* __restrict__ dsts,
                       const float* __restrict__ als, const float* __restrict__ ald,
                       float* __restrict__ wgt, int E) {
  int p = blockIdx.x * blockDim.x + threadIdx.x;
  if (p >= E) return;
  wgt[p] = __expf(lrelu(als[colx[p]] + ald[dsts[p]]));
}

// ---------------- Aggregation, layers 1/2: 4 edge-groups x 16 lanes ----------------

__global__ __launch_bounds__(256) void k_agg128(
    const __half* __restrict__ h, const float* __restrict__ als,
    const float* __restrict__ ald, const int* __restrict__ rowptr,
    const int* __restrict__ colx, const float* __restrict__ wgt,
    const float* __restrict__ bias, float* __restrict__ out, int n, int do_elu) {
  int w = threadIdx.x >> 6, lane = threadIdx.x & 63;
  int node = blockIdx.x * 4 + w;
  if (node >= n) return;
  int g = lane >> 4, q = lane & 15, head = q >> 2;
  int beg = rowptr[node], end = rowptr[node + 1];
  float acc[8] = {};
  float z = 0.f;
  if (g == 0) {  // self loop
    float4 a4 = ((const float4*)als)[node];
    float4 d4 = ((const float4*)ald)[node];
    float ws = __expf(lrelu(sel4(a4.x, a4.y, a4.z, a4.w, head) +
                            sel4(d4.x, d4.y, d4.z, d4.w, head)));
    z = ws;
    float4 raw = *(const float4*)(h + (size_t)node * 128 + q * 8);
    const __half2* hh = (const __half2*)&raw;
#pragma unroll
    for (int j = 0; j < 4; ++j) {
      float2 f = __half22float2(hh[j]);
      acc[2 * j] = ws * f.x;
      acc[2 * j + 1] = ws * f.y;
    }
  }
  for (int i = beg; i < end; i += 4) {
    int e = i + g;
    if (e < end) {
      int s = colx[e];
      float wv = wgt[e * 4 + head];
      float4 raw = *(const float4*)(h + (size_t)s * 128 + q * 8);
      const __half2* hh = (const __half2*)&raw;
      z += wv;
#pragma unroll
      for (int j = 0; j < 4; ++j) {
        float2 f = __half22float2(hh[j]);
        acc[2 * j] = fmaf(wv, f.x, acc[2 * j]);
        acc[2 * j + 1] = fmaf(wv, f.y, acc[2 * j + 1]);
      }
    }
  }
#pragma unroll
  for (int off = 16; off <= 32; off <<= 1) {
    z += __shfl_xor(z, off);
#pragma unroll
    for (int j = 0; j < 8; ++j) acc[j] += __shfl_xor(acc[j], off);
  }
  if (g == 0) {
    float inv = 1.f / z;
    int c0 = q * 8;
    float o[8];
#pragma unroll
    for (int j = 0; j < 8; ++j) {
      float v = acc[j] * inv + bias[c0 + j];
      if (do_elu) v = (v > 0.f) ? v : (__expf(v) - 1.f);
      o[j] = v;
    }
    *(float4*)&out[(size_t)node * 128 + c0] = make_float4(o[0], o[1], o[2], o[3]);
    *(float4*)&out[(size_t)node * 128 + c0 + 4] = make_float4(o[4], o[5], o[6], o[7]);
  }
}

// ---------------- Aggregation, layer 3 ----------------

__global__ __launch_bounds__(256) void k_agg32(
    const float* __restrict__ h, const float* __restrict__ als,
    const float* __restrict__ ald, const int* __restrict__ rowptr,
    const int* __restrict__ colx, const float* __restrict__ wgt,
    const float* __restrict__ bias, float* __restrict__ out, int n) {
  int w = threadIdx.x >> 6, lane = threadIdx.x & 63;
  int node = blockIdx.x * 4 + w;
  if (node >= n) return;
  int g = lane >> 4, q = lane & 15;
  int beg = rowptr[node], end = rowptr[node + 1];
  float acc0 = 0.f, acc1 = 0.f, z = 0.f;
  if (g == 0) {
    float ws = __expf(lrelu(als[node] + ald[node]));
    float2 f = *(const float2*)&h[(size_t)node * 32 + 2 * q];
    z = ws;
    acc0 = ws * f.x;
    acc1 = ws * f.y;
  }
  for (int i = beg; i < end; i += 4) {
    int e = i + g;
    if (e < end) {
      int s = colx[e];
      float wv = wgt[e];
      float2 f = *(const float2*)&h[(size_t)s * 32 + 2 * q];
      z += wv;
      acc0 = fmaf(wv, f.x, acc0);
      acc1 = fmaf(wv, f.y, acc1);
    }
  }
#pragma unroll
  for (int off = 16; off <= 32; off <<= 1) {
    z += __shfl_xor(z, off);
    acc0 += __shfl_xor(acc0, off);
    acc1 += __shfl_xor(acc1, off);
  }
  if (g == 0) {
    float inv = 1.f / z;
    *(float2*)&out[(size_t)node * 32 + 2 * q] =
        make_float2(acc0 * inv + bias[2 * q], acc1 * inv + bias[2 * q + 1]);
  }
}

// ---------------- launch ----------------

extern "C" void kernel_launch(void* const* d_in, const int* in_sizes, int n_in,
                              void* d_out, int out_size, void* d_ws, size_t ws_size,
                              hipStream_t stream) {
  const float* x   = (const float*)d_in[0];
  const int*   ei  = (const int*)d_in[1];
  const float* W1  = (const float*)d_in[4];
  const float* a1s = (const float*)d_in[5];
  const float* a1d = (const float*)d_in[6];
  const float* b1  = (const float*)d_in[7];
  const float* W2  = (const float*)d_in[8];
  const float* a2s = (const float*)d_in[9];
  const float* a2d = (const float*)d_in[10];
  const float* b2  = (const float*)d_in[11];
  const float* W3  = (const float*)d_in[12];
  const float* a3s = (const float*)d_in[13];
  const float* a3d = (const float*)d_in[14];
  const float* b3  = (const float*)d_in[15];
  const int N = in_sizes[0] / 128;
  const int E = in_sizes[1] / 2;
  const int ntiles = (N + 15) / 16;
  const int stride = (N + NB - 1) / NB;

  char* ws = (char*)d_ws;
  size_t off = 0;
  auto alloc = [&](size_t bytes) -> void* {
    void* p = ws + off;
    off += (bytes + 255) & ~(size_t)255;
    return p;
  };
  float*  buf_f = (float*)alloc((size_t)N * 128 * 4);
  __half* h_h   = (__half*)alloc((size_t)N * 128 * 2);
  float*  h32   = (float*)alloc((size_t)N * 32 * 4);
  float*  als   = (float*)alloc((size_t)N * 4 * 4);
  float*  ald   = (float*)alloc((size_t)N * 4 * 4);
  float*  als1  = (float*)alloc((size_t)N * 4);
  float*  ald1  = (float*)alloc((size_t)N * 4);
  int* rowptr   = (int*)alloc((size_t)(N + 1) * 4);
  int* deg      = (int*)alloc((size_t)N * 4);
  int* part     = (int*)alloc(256 * 4);
  int* gcur     = (int*)alloc(NB * 4);
  int2* ebuck   = (int2*)alloc((size_t)E * 8);
  int* colx     = (int*)alloc((size_t)E * 4);
  int* dsts     = (int*)alloc((size_t)E * 4);
  float* wgt4   = (float*)alloc((size_t)E * 4 * 4);
  float* wgt1   = wgt4;
  __half* wf1   = (__half*)alloc(4 * 8 * 64 * 8 * 2);
  __half* wf2   = (__half*)alloc(4 * 8 * 64 * 8 * 2);
  __half* wf3   = (__half*)alloc(4 * 2 * 64 * 8 * 2);
  (void)ws_size; (void)n_in; (void)out_size;

  // CSR build
  hipMemsetAsync(deg, 0, (size_t)N * 4, stream);
  k_hist<<<(E / 4 + 255) / 256, 256, 0, stream>>>(ei + E, E, deg);
  int nb = (N + 255) / 256;
  k_scan1<<<nb, 256, 0, stream>>>(deg, rowptr, part, N);
  k_scan2<<<1, 256, 0, stream>>>(part, nb);
  k_scan3<<<nb, 256, 0, stream>>>(rowptr, part, N, E);
  k_initcur<<<1, 256, 0, stream>>>(rowptr, gcur, stride, N);
  k_bucket<<<(E + EPB - 1) / EPB, 256, 0, stream>>>(ei, E, stride, gcur, ebuck);
  k_fine<<<NB, 256, 0, stream>>>(ebuck, rowptr, colx, dsts, stride, N);

  // W fragment prep
  k_prepW<<<8, 256, 0, stream>>>(W1, wf1, 8);
  k_prepW<<<8, 256, 0, stream>>>(W2, wf2, 8);
  k_prepW<<<2, 256, 0, stream>>>(W3, wf3, 2);

  int gblk = (ntiles + 3) / 4;
  int ebl = (E + 255) / 256;
  // Layer 1
  gemm_mfma<8, 4, __half><<<gblk, 256, 0, stream>>>(x, wf1, a1s, a1d, h_h, als, ald, N, ntiles);
  k_wgt4<<<ebl, 256, 0, stream>>>(colx, dsts, als, ald, wgt4, E);
  k_agg128<<<(N + 3) / 4, 256, 0, stream>>>(h_h, als, ald, rowptr, colx, wgt4, b1, buf_f, N, 1);
  // Layer 2
  gemm_mfma<8, 4, __half><<<gblk, 256, 0, stream>>>(buf_f, wf2, a2s, a2d, h_h, als, ald, N, ntiles);
  k_wgt4<<<ebl, 256, 0, stream>>>(colx, dsts, als, ald, wgt4, E);
  k_agg128<<<(N + 3) / 4, 256, 0, stream>>>(h_h, als, ald, rowptr, colx, wgt4, b2, buf_f, N, 1);
  // Layer 3
  gemm_mfma<2, 1, float><<<gblk, 256, 0, stream>>>(buf_f, wf3, a3s, a3d, h32, als1, ald1, N, ntiles);
  k_wgt1<<<ebl, 256, 0, stream>>>(colx, dsts, als1, ald1, wgt1, E);
  k_agg32<<<(N + 3) / 4, 256, 0, stream>>>(h32, als1, ald1, rowptr, colx, wgt1, b3, (float*)d_out, N);
}

// Round 6
// 234.350 us; speedup vs baseline: 2.7451x; 1.1481x over previous
//
#include <hip/hip_runtime.h>
#include <hip/hip_fp16.h>

#define LRELU_SLOPE 0.2f
#define BSH 8            // bucket shift: stride = 256 nodes
#define EPB 7168         // edges per bucket-sort block (56KB LDS stage)

typedef _Float16 f16x8 __attribute__((ext_vector_type(8)));
typedef float f32x4 __attribute__((ext_vector_type(4)));

__device__ __forceinline__ float lrelu(float x) { return x >= 0.0f ? x : LRELU_SLOPE * x; }

__device__ __forceinline__ float sel4(float a, float b, float c, float d, int h) {
  float r = a;
  r = (h == 1) ? b : r;
  r = (h == 2) ? c : r;
  r = (h == 3) ? d : r;
  return r;
}

// ---------------- CSR build ----------------

__global__ void k_hist(const int* __restrict__ dst, int E, int* __restrict__ deg) {
  int e = (blockIdx.x * blockDim.x + threadIdx.x) * 4;
  if (e + 3 < E) {
    int4 d = *(const int4*)&dst[e];
    atomicAdd(&deg[d.x], 1);
    atomicAdd(&deg[d.y], 1);
    atomicAdd(&deg[d.z], 1);
    atomicAdd(&deg[d.w], 1);
  } else {
    for (; e < E; ++e) atomicAdd(&deg[dst[e]], 1);
  }
}

__global__ __launch_bounds__(256) void k_scan1(const int* __restrict__ deg,
                                               int* __restrict__ rp,
                                               int* __restrict__ part, int n) {
  __shared__ int sm[256];
  int t = threadIdx.x;
  int i = blockIdx.x * 256 + t;
  int v = (i < n) ? deg[i] : 0;
  sm[t] = v;
  __syncthreads();
#pragma unroll
  for (int off = 1; off < 256; off <<= 1) {
    int u = (t >= off) ? sm[t - off] : 0;
    __syncthreads();
    sm[t] += u;
    __syncthreads();
  }
  if (i < n) rp[i] = sm[t] - v;
  if (t == 255) part[blockIdx.x] = sm[255];
}

__global__ __launch_bounds__(256) void k_scan2(int* __restrict__ part, int nb) {
  __shared__ int sm[256];
  int t = threadIdx.x;
  int v = (t < nb) ? part[t] : 0;
  sm[t] = v;
  __syncthreads();
#pragma unroll
  for (int off = 1; off < 256; off <<= 1) {
    int u = (t >= off) ? sm[t - off] : 0;
    __syncthreads();
    sm[t] += u;
    __syncthreads();
  }
  if (t < nb) part[t] = sm[t] - v;
}

// adds block offsets; also emits per-bucket base cursors (gcur) and rowptr[n]
__global__ __launch_bounds__(256) void k_scan3(int* __restrict__ rp,
                                               const int* __restrict__ part,
                                               int* __restrict__ gcur, int n, int E) {
  int t = threadIdx.x;
  int i = blockIdx.x * 256 + t;
  if (i < n) {
    int v = rp[i] + part[blockIdx.x];
    rp[i] = v;
    if ((i & 255) == 0) gcur[i >> BSH] = v;
  }
  if (blockIdx.x == 0 && t == 0) rp[n] = E;
}

// Phase 1: bucket edges by dst>>8; LDS reorder so global writes are grouped runs.
__global__ __launch_bounds__(256) void k_bucket(const int* __restrict__ ei, int E,
                                                int* __restrict__ gcur,
                                                int2* __restrict__ ebuck) {
  __shared__ int2 stage[EPB];
  __shared__ int cnt[256], offs[256], gbase[256], curl[256], sm[256];
  int t = threadIdx.x;
  int base = blockIdx.x * EPB;
  int count = E - base;
  if (count > EPB) count = EPB;
  if (count < 0) count = 0;
  cnt[t] = 0;
  __syncthreads();
  // pass 1: histogram dst buckets
  for (int i = t; i < count; i += 256) {
    int d = ei[E + base + i];
    atomicAdd(&cnt[d >> BSH], 1);
  }
  __syncthreads();
  sm[t] = cnt[t];
  __syncthreads();
#pragma unroll
  for (int off = 1; off < 256; off <<= 1) {
    int u = (t >= off) ? sm[t - off] : 0;
    __syncthreads();
    sm[t] += u;
    __syncthreads();
  }
  offs[t] = sm[t] - cnt[t];
  curl[t] = sm[t] - cnt[t];
  if (cnt[t] > 0) gbase[t] = atomicAdd(&gcur[t], cnt[t]);
  __syncthreads();
  // pass 2: place into LDS grouped by bucket
  for (int i = t; i < count; i += 256) {
    int s = ei[base + i];
    int d = ei[E + base + i];
    int r = atomicAdd(&curl[d >> BSH], 1);
    stage[r] = make_int2(s, d);
  }
  __syncthreads();
  // streaming grouped writes
  for (int i = t; i < count; i += 256) {
    int2 e = stage[i];
    int b = e.y >> BSH;
    ebuck[gbase[b] + (i - offs[b])] = e;
  }
}

// Phase 2: per-bucket fine counting sort; node cursors in LDS, writes L2-local.
__global__ __launch_bounds__(256) void k_fine(const int2* __restrict__ ebuck,
                                              const int* __restrict__ rowptr,
                                              int* __restrict__ colx, int n) {
  __shared__ int cur[256];
  int b = blockIdx.x;
  int lo = b << BSH;
  int hi = lo + 256;
  if (hi > n) hi = n;
  int nn = hi - lo;
  int t = threadIdx.x;
  if (t < nn) cur[t] = rowptr[lo + t];
  __syncthreads();
  int ebeg = rowptr[lo], eend = rowptr[hi];
  for (int i = ebeg + t; i < eend; i += 256) {
    int2 e = ebuck[i];
    int p = atomicAdd(&cur[e.y - lo], 1);
    colx[p] = e.x;
  }
}

// ---------------- W fragment prep: all three layers in one launch ----------------
// frag f = kt*NT + nt; lane l holds B[k = kt*32 + (l>>4)*8 + j][col = nt*16 + (l&15)].

__device__ __forceinline__ void prep_one(const float* __restrict__ W, __half* __restrict__ out,
                                         int NT, int t) {
  int l = t & 63, f = t >> 6;
  int kt = f / NT, nt = f % NT;
  int k0 = kt * 32 + (l >> 4) * 8;
  int col = nt * 16 + (l & 15);
  union { __half h[8]; float4 v; } u;
#pragma unroll
  for (int j = 0; j < 8; ++j) u.h[j] = (__half)W[(size_t)(k0 + j) * (NT * 16) + col];
  *(float4*)(out + (size_t)t * 8) = u.v;
}

__global__ void k_prepW(const float* __restrict__ W1, __half* __restrict__ wf1,
                        const float* __restrict__ W2, __half* __restrict__ wf2,
                        const float* __restrict__ W3, __half* __restrict__ wf3) {
  int t = blockIdx.x * blockDim.x + threadIdx.x;
  if (t < 2048) prep_one(W1, wf1, 8, t);
  else if (t < 4096) prep_one(W2, wf2, 8, t - 2048);
  else if (t < 4608) prep_one(W3, wf3, 2, t - 4096);
}

// ---------------- MFMA GEMM + fused attention logits ----------------

template <int NT, int NH, typename OUT>
__global__ __launch_bounds__(256, 2) void gemm_mfma(
    const float* __restrict__ x, const __half* __restrict__ wfrag,
    const float* __restrict__ a_s, const float* __restrict__ a_d,
    OUT* __restrict__ h, float* __restrict__ als, float* __restrict__ ald,
    int n, int ntiles) {
  int lane = threadIdx.x & 63, w = threadIdx.x >> 6;
  const f16x8* wf = (const f16x8*)wfrag;
  f16x8 B[4][NT];
#pragma unroll
  for (int kt = 0; kt < 4; ++kt)
#pragma unroll
    for (int nt = 0; nt < NT; ++nt) B[kt][nt] = wf[(kt * NT + nt) * 64 + lane];
  int tile = blockIdx.x * 4 + w;
  if (tile >= ntiles) return;
  int r0 = tile * 16;
  int arow = r0 + (lane & 15);
  const float* xp = x + (size_t)arow * 128 + (lane >> 4) * 8;
  bool full = (r0 + 16 <= n);
  f16x8 A[4];
#pragma unroll
  for (int kt = 0; kt < 4; ++kt) {
    float4 lo, hi;
    if (full || arow < n) {
      lo = *(const float4*)(xp + kt * 32);
      hi = *(const float4*)(xp + kt * 32 + 4);
    } else {
      lo = make_float4(0.f, 0.f, 0.f, 0.f);
      hi = lo;
    }
    f16x8 a;
    a[0] = (_Float16)lo.x; a[1] = (_Float16)lo.y; a[2] = (_Float16)lo.z; a[3] = (_Float16)lo.w;
    a[4] = (_Float16)hi.x; a[5] = (_Float16)hi.y; a[6] = (_Float16)hi.z; a[7] = (_Float16)hi.w;
    A[kt] = a;
  }
  f32x4 acc[NT];
#pragma unroll
  for (int nt = 0; nt < NT; ++nt) acc[nt] = (f32x4){0.f, 0.f, 0.f, 0.f};
#pragma unroll
  for (int kt = 0; kt < 4; ++kt)
#pragma unroll
    for (int nt = 0; nt < NT; ++nt)
      acc[nt] = __builtin_amdgcn_mfma_f32_16x16x32_f16(A[kt], B[kt][nt], acc[nt], 0, 0, 0);
  int cb = lane & 15, rb = (lane >> 4) * 4;
  float asv[NT], adv[NT];
#pragma unroll
  for (int nt = 0; nt < NT; ++nt) {
    asv[nt] = a_s[nt * 16 + cb];
    adv[nt] = a_d[nt * 16 + cb];
  }
#pragma unroll
  for (int r = 0; r < 4; ++r) {
    int row = r0 + rb + r;
    if (!full && row >= n) break;
#pragma unroll
    for (int nt = 0; nt < NT; ++nt)
      h[(size_t)row * (NT * 16) + nt * 16 + cb] = (OUT)acc[nt][r];
    if (NH == 4) {
      float ps[4], pd[4];
#pragma unroll
      for (int hh = 0; hh < 4; ++hh) {
        ps[hh] = acc[2 * hh][r] * asv[2 * hh] + acc[2 * hh + 1][r] * asv[2 * hh + 1];
        pd[hh] = acc[2 * hh][r] * adv[2 * hh] + acc[2 * hh + 1][r] * adv[2 * hh + 1];
      }
#pragma unroll
      for (int off = 1; off < 16; off <<= 1) {
#pragma unroll
        for (int hh = 0; hh < 4; ++hh) {
          ps[hh] += __shfl_xor(ps[hh], off);
          pd[hh] += __shfl_xor(pd[hh], off);
        }
      }
      if (cb < 4) {
        als[row * 4 + cb] = sel4(ps[0], ps[1], ps[2], ps[3], cb);
        ald[row * 4 + cb] = sel4(pd[0], pd[1], pd[2], pd[3], cb);
      }
    } else {
      float ps = acc[0][r] * asv[0] + acc[1][r] * asv[1];
      float pd = acc[0][r] * adv[0] + acc[1][r] * adv[1];
#pragma unroll
      for (int off = 1; off < 16; off <<= 1) {
        ps += __shfl_xor(ps, off);
        pd += __shfl_xor(pd, off);
      }
      if (cb == 0) { als[row] = ps; ald[row] = pd; }
    }
  }
}

// ---------------- Aggregation, layers 1/2: fused weights, 4 edge-groups x 16 lanes ----------------
// lane = (g,q): g=lane>>4 edge group, q=lane&15 owns channels 8q..8q+7 (head=q>>2).
// wv = exp(lrelu(als[s][head] + ald[node][head])) computed inline (als L2-hot, 800KB).

__global__ __launch_bounds__(256) void k_agg128(
    const __half* __restrict__ h, const float* __restrict__ als,
    const float* __restrict__ ald, const int* __restrict__ rowptr,
    const int* __restrict__ colx, const float* __restrict__ bias,
    float* __restrict__ out, int n, int do_elu) {
  int w = threadIdx.x >> 6, lane = threadIdx.x & 63;
  int node = blockIdx.x * 4 + w;
  if (node >= n) return;
  int g = lane >> 4, q = lane & 15, head = q >> 2;
  int beg = rowptr[node], end = rowptr[node + 1];
  float adh = ald[node * 4 + head];
  float acc[8] = {};
  float z = 0.f;
  if (g == 0) {  // self loop
    float ws = __expf(lrelu(als[node * 4 + head] + adh));
    z = ws;
    float4 raw = *(const float4*)(h + (size_t)node * 128 + q * 8);
    const __half2* hh = (const __half2*)&raw;
#pragma unroll
    for (int j = 0; j < 4; ++j) {
      float2 f = __half22float2(hh[j]);
      acc[2 * j] = ws * f.x;
      acc[2 * j + 1] = ws * f.y;
    }
  }
  for (int e = beg + g; e < end; e += 4) {
    int s = colx[e];
    float wv = __expf(lrelu(als[s * 4 + head] + adh));
    float4 raw = *(const float4*)(h + (size_t)s * 128 + q * 8);
    const __half2* hh = (const __half2*)&raw;
    z += wv;
#pragma unroll
    for (int j = 0; j < 4; ++j) {
      float2 f = __half22float2(hh[j]);
      acc[2 * j] = fmaf(wv, f.x, acc[2 * j]);
      acc[2 * j + 1] = fmaf(wv, f.y, acc[2 * j + 1]);
    }
  }
#pragma unroll
  for (int off = 16; off <= 32; off <<= 1) {
    z += __shfl_xor(z, off);
#pragma unroll
    for (int j = 0; j < 8; ++j) acc[j] += __shfl_xor(acc[j], off);
  }
  if (g == 0) {
    float inv = 1.f / z;
    int c0 = q * 8;
    float o[8];
#pragma unroll
    for (int j = 0; j < 8; ++j) {
      float v = acc[j] * inv + bias[c0 + j];
      if (do_elu) v = (v > 0.f) ? v : (__expf(v) - 1.f);
      o[j] = v;
    }
    *(float4*)&out[(size_t)node * 128 + c0] = make_float4(o[0], o[1], o[2], o[3]);
    *(float4*)&out[(size_t)node * 128 + c0 + 4] = make_float4(o[4], o[5], o[6], o[7]);
  }
}

// ---------------- Aggregation, layer 3: fused weights ----------------

__global__ __launch_bounds__(256) void k_agg32(
    const float* __restrict__ h, const float* __restrict__ als,
    const float* __restrict__ ald, const int* __restrict__ rowptr,
    const int* __restrict__ colx, const float* __restrict__ bias,
    float* __restrict__ out, int n) {
  int w = threadIdx.x >> 6, lane = threadIdx.x & 63;
  int node = blockIdx.x * 4 + w;
  if (node >= n) return;
  int g = lane >> 4, q = lane & 15;
  int beg = rowptr[node], end = rowptr[node + 1];
  float ad = ald[node];
  float acc0 = 0.f, acc1 = 0.f, z = 0.f;
  if (g == 0) {
    float ws = __expf(lrelu(als[node] + ad));
    float2 f = *(const float2*)&h[(size_t)node * 32 + 2 * q];
    z = ws;
    acc0 = ws * f.x;
    acc1 = ws * f.y;
  }
  for (int e = beg + g; e < end; e += 4) {
    int s = colx[e];
    float wv = __expf(lrelu(als[s] + ad));
    float2 f = *(const float2*)&h[(size_t)s * 32 + 2 * q];
    z += wv;
    acc0 = fmaf(wv, f.x, acc0);
    acc1 = fmaf(wv, f.y, acc1);
  }
#pragma unroll
  for (int off = 16; off <= 32; off <<= 1) {
    z += __shfl_xor(z, off);
    acc0 += __shfl_xor(acc0, off);
    acc1 += __shfl_xor(acc1, off);
  }
  if (g == 0) {
    float inv = 1.f / z;
    *(float2*)&out[(size_t)node * 32 + 2 * q] =
        make_float2(acc0 * inv + bias[2 * q], acc1 * inv + bias[2 * q + 1]);
  }
}

// ---------------- launch ----------------

extern "C" void kernel_launch(void* const* d_in, const int* in_sizes, int n_in,
                              void* d_out, int out_size, void* d_ws, size_t ws_size,
                              hipStream_t stream) {
  const float* x   = (const float*)d_in[0];
  const int*   ei  = (const int*)d_in[1];
  const float* W1  = (const float*)d_in[4];
  const float* a1s = (const float*)d_in[5];
  const float* a1d = (const float*)d_in[6];
  const float* b1  = (const float*)d_in[7];
  const float* W2  = (const float*)d_in[8];
  const float* a2s = (const float*)d_in[9];
  const float* a2d = (const float*)d_in[10];
  const float* b2  = (const float*)d_in[11];
  const float* W3  = (const float*)d_in[12];
  const float* a3s = (const float*)d_in[13];
  const float* a3d = (const float*)d_in[14];
  const float* b3  = (const float*)d_in[15];
  const int N = in_sizes[0] / 128;
  const int E = in_sizes[1] / 2;
  const int ntiles = (N + 15) / 16;
  const int nbuck = (N + 255) >> BSH;

  char* ws = (char*)d_ws;
  size_t off = 0;
  auto alloc = [&](size_t bytes) -> void* {
    void* p = ws + off;
    off += (bytes + 255) & ~(size_t)255;
    return p;
  };
  float*  buf_f = (float*)alloc((size_t)N * 128 * 4);
  __half* h_h   = (__half*)alloc((size_t)N * 128 * 2);
  float*  h32   = (float*)alloc((size_t)N * 32 * 4);
  float*  als   = (float*)alloc((size_t)N * 4 * 4);
  float*  ald   = (float*)alloc((size_t)N * 4 * 4);
  float*  als1  = (float*)alloc((size_t)N * 4);
  float*  ald1  = (float*)alloc((size_t)N * 4);
  int* rowptr   = (int*)alloc((size_t)(N + 1) * 4);
  int* deg      = (int*)alloc((size_t)N * 4);
  int* part     = (int*)alloc(256 * 4);
  int* gcur     = (int*)alloc(256 * 4);
  int2* ebuck   = (int2*)alloc((size_t)E * 8);
  int* colx     = (int*)alloc((size_t)E * 4);
  __half* wf1   = (__half*)alloc(4 * 8 * 64 * 8 * 2);
  __half* wf2   = (__half*)alloc(4 * 8 * 64 * 8 * 2);
  __half* wf3   = (__half*)alloc(4 * 2 * 64 * 8 * 2);
  (void)ws_size; (void)n_in; (void)out_size;

  // CSR build (graph identical for all 3 layers)
  hipMemsetAsync(deg, 0, (size_t)N * 4, stream);
  k_hist<<<(E / 4 + 255) / 256, 256, 0, stream>>>(ei + E, E, deg);
  int nb = (N + 255) / 256;
  k_scan1<<<nb, 256, 0, stream>>>(deg, rowptr, part, N);
  k_scan2<<<1, 256, 0, stream>>>(part, nb);
  k_scan3<<<nb, 256, 0, stream>>>(rowptr, part, gcur, N, E);
  k_bucket<<<(E + EPB - 1) / EPB, 256, 0, stream>>>(ei, E, gcur, ebuck);
  k_fine<<<nbuck, 256, 0, stream>>>(ebuck, rowptr, colx, N);

  // W fragment prep (all layers, one launch)
  k_prepW<<<18, 256, 0, stream>>>(W1, wf1, W2, wf2, W3, wf3);

  int gblk = (ntiles + 3) / 4;
  // Layer 1
  gemm_mfma<8, 4, __half><<<gblk, 256, 0, stream>>>(x, wf1, a1s, a1d, h_h, als, ald, N, ntiles);
  k_agg128<<<(N + 3) / 4, 256, 0, stream>>>(h_h, als, ald, rowptr, colx, b1, buf_f, N, 1);
  // Layer 2
  gemm_mfma<8, 4, __half><<<gblk, 256, 0, stream>>>(buf_f, wf2, a2s, a2d, h_h, als, ald, N, ntiles);
  k_agg128<<<(N + 3) / 4, 256, 0, stream>>>(h_h, als, ald, rowptr, colx, b2, buf_f, N, 1);
  // Layer 3
  gemm_mfma<2, 1, float><<<gblk, 256, 0, stream>>>(buf_f, wf3, a3s, a3d, h32, als1, ald1, N, ntiles);
  k_agg32<<<(N + 3) / 4, 256, 0, stream>>>(h32, als1, ald1, rowptr, colx, b3, (float*)d_out, N);
}

// Round 7
// 225.631 us; speedup vs baseline: 2.8512x; 1.0386x over previous
//
#include <hip/hip_runtime.h>
#include <hip/hip_fp16.h>

#define LRELU_SLOPE 0.2f
#define BSH 8            // bucket shift: stride = 256 nodes
#define EPB 7168         // edges per bucket-sort block (56KB LDS stage)

typedef _Float16 f16x8 __attribute__((ext_vector_type(8)));
typedef float f32x4 __attribute__((ext_vector_type(4)));

__device__ __forceinline__ float lrelu(float x) { return x >= 0.0f ? x : LRELU_SLOPE * x; }

__device__ __forceinline__ float sel4(float a, float b, float c, float d, int h) {
  float r = a;
  r = (h == 1) ? b : r;
  r = (h == 2) ? c : r;
  r = (h == 3) ? d : r;
  return r;
}

// ---------------- W fragment prep ----------------
// frag f = kt*NT + nt; lane l holds B[k = kt*32 + (l>>4)*8 + j][col = nt*16 + (l&15)].

__device__ __forceinline__ void prep_one(const float* __restrict__ W, __half* __restrict__ out,
                                         int NT, int t) {
  int l = t & 63, f = t >> 6;
  int kt = f / NT, nt = f % NT;
  int k0 = kt * 32 + (l >> 4) * 8;
  int col = nt * 16 + (l & 15);
  union { __half h[8]; float4 v; } u;
#pragma unroll
  for (int j = 0; j < 8; ++j) u.h[j] = (__half)W[(size_t)(k0 + j) * (NT * 16) + col];
  *(float4*)(out + (size_t)t * 8) = u.v;
}

// ---------------- CSR build (hist + fused prepW in extra blocks) ----------------

__global__ void k_hist(const int* __restrict__ dst, int E, int* __restrict__ deg, int histBlocks,
                       const float* __restrict__ W1, __half* __restrict__ wf1,
                       const float* __restrict__ W2, __half* __restrict__ wf2,
                       const float* __restrict__ W3, __half* __restrict__ wf3) {
  if (blockIdx.x >= histBlocks) {
    int t = (blockIdx.x - histBlocks) * 256 + threadIdx.x;
    if (t < 2048) prep_one(W1, wf1, 8, t);
    else if (t < 4096) prep_one(W2, wf2, 8, t - 2048);
    else if (t < 4608) prep_one(W3, wf3, 2, t - 4096);
    return;
  }
  int e = (blockIdx.x * blockDim.x + threadIdx.x) * 4;
  if (e + 3 < E) {
    int4 d = *(const int4*)&dst[e];
    atomicAdd(&deg[d.x], 1);
    atomicAdd(&deg[d.y], 1);
    atomicAdd(&deg[d.z], 1);
    atomicAdd(&deg[d.w], 1);
  } else {
    for (; e < E; ++e) atomicAdd(&deg[dst[e]], 1);
  }
}

__global__ __launch_bounds__(256) void k_scan1(const int* __restrict__ deg,
                                               int* __restrict__ rp,
                                               int* __restrict__ part, int n) {
  __shared__ int sm[256];
  int t = threadIdx.x;
  int i = blockIdx.x * 256 + t;
  int v = (i < n) ? deg[i] : 0;
  sm[t] = v;
  __syncthreads();
#pragma unroll
  for (int off = 1; off < 256; off <<= 1) {
    int u = (t >= off) ? sm[t - off] : 0;
    __syncthreads();
    sm[t] += u;
    __syncthreads();
  }
  if (i < n) rp[i] = sm[t] - v;
  if (t == 255) part[blockIdx.x] = sm[255];
}

__global__ __launch_bounds__(256) void k_scan2(int* __restrict__ part, int nb) {
  __shared__ int sm[256];
  int t = threadIdx.x;
  int v = (t < nb) ? part[t] : 0;
  sm[t] = v;
  __syncthreads();
#pragma unroll
  for (int off = 1; off < 256; off <<= 1) {
    int u = (t >= off) ? sm[t - off] : 0;
    __syncthreads();
    sm[t] += u;
    __syncthreads();
  }
  if (t < nb) part[t] = sm[t] - v;
}

__global__ __launch_bounds__(256) void k_scan3(int* __restrict__ rp,
                                               const int* __restrict__ part,
                                               int* __restrict__ gcur, int n, int E) {
  int t = threadIdx.x;
  int i = blockIdx.x * 256 + t;
  if (i < n) {
    int v = rp[i] + part[blockIdx.x];
    rp[i] = v;
    if ((i & 255) == 0) gcur[i >> BSH] = v;
  }
  if (blockIdx.x == 0 && t == 0) rp[n] = E;
}

// Phase 1: bucket edges by dst>>8; LDS reorder so global writes are grouped runs.
__global__ __launch_bounds__(256) void k_bucket(const int* __restrict__ ei, int E,
                                                int* __restrict__ gcur,
                                                int2* __restrict__ ebuck) {
  __shared__ int2 stage[EPB];
  __shared__ int cnt[256], offs[256], gbase[256], curl[256], sm[256];
  int t = threadIdx.x;
  int base = blockIdx.x * EPB;
  int count = E - base;
  if (count > EPB) count = EPB;
  if (count < 0) count = 0;
  cnt[t] = 0;
  __syncthreads();
  for (int i = t; i < count; i += 256) {
    int d = ei[E + base + i];
    atomicAdd(&cnt[d >> BSH], 1);
  }
  __syncthreads();
  sm[t] = cnt[t];
  __syncthreads();
#pragma unroll
  for (int off = 1; off < 256; off <<= 1) {
    int u = (t >= off) ? sm[t - off] : 0;
    __syncthreads();
    sm[t] += u;
    __syncthreads();
  }
  offs[t] = sm[t] - cnt[t];
  curl[t] = sm[t] - cnt[t];
  if (cnt[t] > 0) gbase[t] = atomicAdd(&gcur[t], cnt[t]);
  __syncthreads();
  for (int i = t; i < count; i += 256) {
    int s = ei[base + i];
    int d = ei[E + base + i];
    int r = atomicAdd(&curl[d >> BSH], 1);
    stage[r] = make_int2(s, d);
  }
  __syncthreads();
  for (int i = t; i < count; i += 256) {
    int2 e = stage[i];
    int b = e.y >> BSH;
    ebuck[gbase[b] + (i - offs[b])] = e;
  }
}

// Phase 2: per-bucket fine counting sort; node cursors in LDS, writes L2-local.
__global__ __launch_bounds__(256) void k_fine(const int2* __restrict__ ebuck,
                                              const int* __restrict__ rowptr,
                                              int* __restrict__ colx, int n) {
  __shared__ int cur[256];
  int b = blockIdx.x;
  int lo = b << BSH;
  int hi = lo + 256;
  if (hi > n) hi = n;
  int nn = hi - lo;
  int t = threadIdx.x;
  if (t < nn) cur[t] = rowptr[lo + t];
  __syncthreads();
  int ebeg = rowptr[lo], eend = rowptr[hi];
  for (int i = ebeg + t; i < eend; i += 256) {
    int2 e = ebuck[i];
    int p = atomicAdd(&cur[e.y - lo], 1);
    colx[p] = e.x;
  }
}

// ---------------- MFMA GEMM + fused attention logits ----------------
// A-fragment loaders: fp32 source (converts) or fp16 source (direct 16B load).

__device__ __forceinline__ f16x8 load_a(const float* xp) {
  float4 lo = *(const float4*)xp;
  float4 hi = *(const float4*)(xp + 4);
  f16x8 a;
  a[0] = (_Float16)lo.x; a[1] = (_Float16)lo.y; a[2] = (_Float16)lo.z; a[3] = (_Float16)lo.w;
  a[4] = (_Float16)hi.x; a[5] = (_Float16)hi.y; a[6] = (_Float16)hi.z; a[7] = (_Float16)hi.w;
  return a;
}

__device__ __forceinline__ f16x8 load_a(const __half* xp) {
  return *(const f16x8*)xp;
}

template <int NT, int NH, typename IN, typename OUT>
__global__ __launch_bounds__(256, 2) void gemm_mfma(
    const IN* __restrict__ x, const __half* __restrict__ wfrag,
    const float* __restrict__ a_s, const float* __restrict__ a_d,
    OUT* __restrict__ h, float* __restrict__ als, float* __restrict__ ald,
    int n, int ntiles) {
  int lane = threadIdx.x & 63, w = threadIdx.x >> 6;
  const f16x8* wf = (const f16x8*)wfrag;
  f16x8 B[4][NT];
#pragma unroll
  for (int kt = 0; kt < 4; ++kt)
#pragma unroll
    for (int nt = 0; nt < NT; ++nt) B[kt][nt] = wf[(kt * NT + nt) * 64 + lane];
  int tile = blockIdx.x * 4 + w;
  if (tile >= ntiles) return;
  int r0 = tile * 16;
  int arow = r0 + (lane & 15);
  const IN* xp = x + (size_t)arow * 128 + (lane >> 4) * 8;
  bool full = (r0 + 16 <= n);
  f16x8 A[4];
#pragma unroll
  for (int kt = 0; kt < 4; ++kt) {
    if (full || arow < n) A[kt] = load_a(xp + kt * 32);
    else A[kt] = (f16x8){};
  }
  f32x4 acc[NT];
#pragma unroll
  for (int nt = 0; nt < NT; ++nt) acc[nt] = (f32x4){0.f, 0.f, 0.f, 0.f};
#pragma unroll
  for (int kt = 0; kt < 4; ++kt)
#pragma unroll
    for (int nt = 0; nt < NT; ++nt)
      acc[nt] = __builtin_amdgcn_mfma_f32_16x16x32_f16(A[kt], B[kt][nt], acc[nt], 0, 0, 0);
  int cb = lane & 15, rb = (lane >> 4) * 4;
  float asv[NT], adv[NT];
#pragma unroll
  for (int nt = 0; nt < NT; ++nt) {
    asv[nt] = a_s[nt * 16 + cb];
    adv[nt] = a_d[nt * 16 + cb];
  }
#pragma unroll
  for (int r = 0; r < 4; ++r) {
    int row = r0 + rb + r;
    if (!full && row >= n) break;
#pragma unroll
    for (int nt = 0; nt < NT; ++nt)
      h[(size_t)row * (NT * 16) + nt * 16 + cb] = (OUT)acc[nt][r];
    if (NH == 4) {
      float ps[4], pd[4];
#pragma unroll
      for (int hh = 0; hh < 4; ++hh) {
        ps[hh] = acc[2 * hh][r] * asv[2 * hh] + acc[2 * hh + 1][r] * asv[2 * hh + 1];
        pd[hh] = acc[2 * hh][r] * adv[2 * hh] + acc[2 * hh + 1][r] * adv[2 * hh + 1];
      }
#pragma unroll
      for (int off = 1; off < 16; off <<= 1) {
#pragma unroll
        for (int hh = 0; hh < 4; ++hh) {
          ps[hh] += __shfl_xor(ps[hh], off);
          pd[hh] += __shfl_xor(pd[hh], off);
        }
      }
      if (cb < 4) {
        als[row * 4 + cb] = sel4(ps[0], ps[1], ps[2], ps[3], cb);
        ald[row * 4 + cb] = sel4(pd[0], pd[1], pd[2], pd[3], cb);
      }
    } else {
      float ps = acc[0][r] * asv[0] + acc[1][r] * asv[1];
      float pd = acc[0][r] * adv[0] + acc[1][r] * adv[1];
#pragma unroll
      for (int off = 1; off < 16; off <<= 1) {
        ps += __shfl_xor(ps, off);
        pd += __shfl_xor(pd, off);
      }
      if (cb == 0) { als[row] = ps; ald[row] = pd; }
    }
  }
}

// ---------------- Aggregation, layers 1/2: fused weights, fp16 out ----------------
// lane = (g,q): g=lane>>4 edge group, q=lane&15 owns channels 8q..8q+7 (head=q>>2).

__global__ __launch_bounds__(256) void k_agg128(
    const __half* __restrict__ h, const float* __restrict__ als,
    const float* __restrict__ ald, const int* __restrict__ rowptr,
    const int* __restrict__ colx, const float* __restrict__ bias,
    __half* __restrict__ out, int n) {
  int w = threadIdx.x >> 6, lane = threadIdx.x & 63;
  int node = blockIdx.x * 4 + w;
  if (node >= n) return;
  int g = lane >> 4, q = lane & 15, head = q >> 2;
  int beg = rowptr[node], end = rowptr[node + 1];
  float adh = ald[node * 4 + head];
  float acc[8] = {};
  float z = 0.f;
  if (g == 0) {  // self loop
    float ws = __expf(lrelu(als[node * 4 + head] + adh));
    z = ws;
    float4 raw = *(const float4*)(h + (size_t)node * 128 + q * 8);
    const __half2* hh = (const __half2*)&raw;
#pragma unroll
    for (int j = 0; j < 4; ++j) {
      float2 f = __half22float2(hh[j]);
      acc[2 * j] = ws * f.x;
      acc[2 * j + 1] = ws * f.y;
    }
  }
  for (int e = beg + g; e < end; e += 4) {
    int s = colx[e];
    float wv = __expf(lrelu(als[s * 4 + head] + adh));
    float4 raw = *(const float4*)(h + (size_t)s * 128 + q * 8);
    const __half2* hh = (const __half2*)&raw;
    z += wv;
#pragma unroll
    for (int j = 0; j < 4; ++j) {
      float2 f = __half22float2(hh[j]);
      acc[2 * j] = fmaf(wv, f.x, acc[2 * j]);
      acc[2 * j + 1] = fmaf(wv, f.y, acc[2 * j + 1]);
    }
  }
#pragma unroll
  for (int off = 16; off <= 32; off <<= 1) {
    z += __shfl_xor(z, off);
#pragma unroll
    for (int j = 0; j < 8; ++j) acc[j] += __shfl_xor(acc[j], off);
  }
  if (g == 0) {
    float inv = 1.f / z;
    int c0 = q * 8;
    union { __half h8[8]; float4 v; } u;
#pragma unroll
    for (int j = 0; j < 8; ++j) {
      float v = acc[j] * inv + bias[c0 + j];
      v = (v > 0.f) ? v : (__expf(v) - 1.f);  // elu
      u.h8[j] = (__half)v;
    }
    *(float4*)&out[(size_t)node * 128 + c0] = u.v;
  }
}

// ---------------- Aggregation, layer 3: fp16 gather, fp32 out ----------------

__global__ __launch_bounds__(256) void k_agg32(
    const __half* __restrict__ h, const float* __restrict__ als,
    const float* __restrict__ ald, const int* __restrict__ rowptr,
    const int* __restrict__ colx, const float* __restrict__ bias,
    float* __restrict__ out, int n) {
  int w = threadIdx.x >> 6, lane = threadIdx.x & 63;
  int node = blockIdx.x * 4 + w;
  if (node >= n) return;
  int g = lane >> 4, q = lane & 15;
  int beg = rowptr[node], end = rowptr[node + 1];
  float ad = ald[node];
  float acc0 = 0.f, acc1 = 0.f, z = 0.f;
  if (g == 0) {
    float ws = __expf(lrelu(als[node] + ad));
    float2 f = __half22float2(*(const __half2*)&h[(size_t)node * 32 + 2 * q]);
    z = ws;
    acc0 = ws * f.x;
    acc1 = ws * f.y;
  }
  for (int e = beg + g; e < end; e += 4) {
    int s = colx[e];
    float wv = __expf(lrelu(als[s] + ad));
    float2 f = __half22float2(*(const __half2*)&h[(size_t)s * 32 + 2 * q]);
    z += wv;
    acc0 = fmaf(wv, f.x, acc0);
    acc1 = fmaf(wv, f.y, acc1);
  }
#pragma unroll
  for (int off = 16; off <= 32; off <<= 1) {
    z += __shfl_xor(z, off);
    acc0 += __shfl_xor(acc0, off);
    acc1 += __shfl_xor(acc1, off);
  }
  if (g == 0) {
    float inv = 1.f / z;
    *(float2*)&out[(size_t)node * 32 + 2 * q] =
        make_float2(acc0 * inv + bias[2 * q], acc1 * inv + bias[2 * q + 1]);
  }
}

// ---------------- launch ----------------

extern "C" void kernel_launch(void* const* d_in, const int* in_sizes, int n_in,
                              void* d_out, int out_size, void* d_ws, size_t ws_size,
                              hipStream_t stream) {
  const float* x   = (const float*)d_in[0];
  const int*   ei  = (const int*)d_in[1];
  const float* W1  = (const float*)d_in[4];
  const float* a1s = (const float*)d_in[5];
  const float* a1d = (const float*)d_in[6];
  const float* b1  = (const float*)d_in[7];
  const float* W2  = (const float*)d_in[8];
  const float* a2s = (const float*)d_in[9];
  const float* a2d = (const float*)d_in[10];
  const float* b2  = (const float*)d_in[11];
  const float* W3  = (const float*)d_in[12];
  const float* a3s = (const float*)d_in[13];
  const float* a3d = (const float*)d_in[14];
  const float* b3  = (const float*)d_in[15];
  const int N = in_sizes[0] / 128;
  const int E = in_sizes[1] / 2;
  const int ntiles = (N + 15) / 16;
  const int nbuck = (N + 255) >> BSH;

  char* ws = (char*)d_ws;
  size_t off = 0;
  auto alloc = [&](size_t bytes) -> void* {
    void* p = ws + off;
    off += (bytes + 255) & ~(size_t)255;
    return p;
  };
  __half* hA    = (__half*)alloc((size_t)N * 128 * 2);  // gemm out (pre-agg features)
  __half* hB    = (__half*)alloc((size_t)N * 128 * 2);  // agg out (next-layer input)
  __half* h32   = (__half*)alloc((size_t)N * 32 * 2);   // layer-3 features
  float*  als   = (float*)alloc((size_t)N * 4 * 4);
  float*  ald   = (float*)alloc((size_t)N * 4 * 4);
  float*  als1  = (float*)alloc((size_t)N * 4);
  float*  ald1  = (float*)alloc((size_t)N * 4);
  int* rowptr   = (int*)alloc((size_t)(N + 1) * 4);
  int* deg      = (int*)alloc((size_t)N * 4);
  int* part     = (int*)alloc(256 * 4);
  int* gcur     = (int*)alloc(256 * 4);
  int2* ebuck   = (int2*)alloc((size_t)E * 8);
  int* colx     = (int*)alloc((size_t)E * 4);
  __half* wf1   = (__half*)alloc(4 * 8 * 64 * 8 * 2);
  __half* wf2   = (__half*)alloc(4 * 8 * 64 * 8 * 2);
  __half* wf3   = (__half*)alloc(4 * 2 * 64 * 8 * 2);
  (void)ws_size; (void)n_in; (void)out_size;

  // CSR build + W prep (graph identical for all 3 layers)
  hipMemsetAsync(deg, 0, (size_t)N * 4, stream);
  int histBlocks = (E / 4 + 255) / 256;
  k_hist<<<histBlocks + 18, 256, 0, stream>>>(ei + E, E, deg, histBlocks,
                                              W1, wf1, W2, wf2, W3, wf3);
  int nb = (N + 255) / 256;
  k_scan1<<<nb, 256, 0, stream>>>(deg, rowptr, part, N);
  k_scan2<<<1, 256, 0, stream>>>(part, nb);
  k_scan3<<<nb, 256, 0, stream>>>(rowptr, part, gcur, N, E);
  k_bucket<<<(E + EPB - 1) / EPB, 256, 0, stream>>>(ei, E, gcur, ebuck);
  k_fine<<<nbuck, 256, 0, stream>>>(ebuck, rowptr, colx, N);

  int gblk = (ntiles + 3) / 4;
  // Layer 1 (fp32 input)
  gemm_mfma<8, 4, float, __half><<<gblk, 256, 0, stream>>>(x, wf1, a1s, a1d, hA, als, ald, N, ntiles);
  k_agg128<<<(N + 3) / 4, 256, 0, stream>>>(hA, als, ald, rowptr, colx, b1, hB, N);
  // Layer 2 (fp16 input)
  gemm_mfma<8, 4, __half, __half><<<gblk, 256, 0, stream>>>(hB, wf2, a2s, a2d, hA, als, ald, N, ntiles);
  k_agg128<<<(N + 3) / 4, 256, 0, stream>>>(hA, als, ald, rowptr, colx, b2, hB, N);
  // Layer 3 (fp16 input, fp16 h, fp32 final out)
  gemm_mfma<2, 1, __half, __half><<<gblk, 256, 0, stream>>>(hB, wf3, a3s, a3d, h32, als1, ald1, N, ntiles);
  k_agg32<<<(N + 3) / 4, 256, 0, stream>>>(h32, als1, ald1, rowptr, colx, b3, (float*)d_out, N);
}

// Round 8
// 203.969 us; speedup vs baseline: 3.1540x; 1.1062x over previous
//
#include <hip/hip_runtime.h>
#include <hip/hip_fp16.h>

#define LRELU_SLOPE 0.2f
#define BSH 8            // bucket shift: 256 nodes per bucket
#define EPB 7168         // edges per bucket-sort block (56KB LDS stage)

typedef _Float16 f16x8 __attribute__((ext_vector_type(8)));
typedef float f32x4 __attribute__((ext_vector_type(4)));

__device__ __forceinline__ float lrelu(float x) { return x >= 0.0f ? x : LRELU_SLOPE * x; }

__device__ __forceinline__ float sel4(float a, float b, float c, float d, int h) {
  float r = a;
  r = (h == 1) ? b : r;
  r = (h == 2) ? c : r;
  r = (h == 3) ? d : r;
  return r;
}

// ---------------- W fragment prep ----------------
// frag f = kt*NT + nt; lane l holds B[k = kt*32 + (l>>4)*8 + j][col = nt*16 + (l&15)].

__device__ __forceinline__ void prep_one(const float* __restrict__ W, __half* __restrict__ out,
                                         int NT, int t) {
  int l = t & 63, f = t >> 6;
  int kt = f / NT, nt = f % NT;
  int k0 = kt * 32 + (l >> 4) * 8;
  int col = nt * 16 + (l & 15);
  union { __half h[8]; float4 v; } u;
#pragma unroll
  for (int j = 0; j < 8; ++j) u.h[j] = (__half)W[(size_t)(k0 + j) * (NT * 16) + col];
  *(float4*)(out + (size_t)t * 8) = u.v;
}

// ---------------- CSR build ----------------

__global__ void k_zero(int* __restrict__ bcnt) { bcnt[threadIdx.x] = 0; }

// bucket-level histogram (LDS-staged) + fused prepW in extra blocks
__global__ __launch_bounds__(256) void k_bcnt(
    const int* __restrict__ dst, int E, int* __restrict__ bcnt, int cntBlocks,
    const float* __restrict__ W1, __half* __restrict__ wf1,
    const float* __restrict__ W2, __half* __restrict__ wf2,
    const float* __restrict__ W3, __half* __restrict__ wf3) {
  if (blockIdx.x >= cntBlocks) {
    int t = (blockIdx.x - cntBlocks) * 256 + threadIdx.x;
    if (t < 2048) prep_one(W1, wf1, 8, t);
    else if (t < 4096) prep_one(W2, wf2, 8, t - 2048);
    else if (t < 4608) prep_one(W3, wf3, 2, t - 4096);
    return;
  }
  __shared__ int c[256];
  int t = threadIdx.x;
  c[t] = 0;
  __syncthreads();
  int e = (blockIdx.x * 256 + t) * 4;
  if (e + 3 < E) {
    int4 d = *(const int4*)&dst[e];
    atomicAdd(&c[d.x >> BSH], 1);
    atomicAdd(&c[d.y >> BSH], 1);
    atomicAdd(&c[d.z >> BSH], 1);
    atomicAdd(&c[d.w >> BSH], 1);
  } else {
    for (; e < E; ++e) atomicAdd(&c[dst[e] >> BSH], 1);
  }
  __syncthreads();
  if (c[t] > 0) atomicAdd(&bcnt[t], c[t]);
}

// scan 256 bucket totals -> cursors (gcur, consumed by k_bucket) + stable bases (bbase)
__global__ __launch_bounds__(256) void k_bscan(const int* __restrict__ bcnt,
                                               int* __restrict__ gcur,
                                               int* __restrict__ bbase, int E) {
  __shared__ int sm[256];
  int t = threadIdx.x;
  int v = bcnt[t];
  sm[t] = v;
  __syncthreads();
#pragma unroll
  for (int off = 1; off < 256; off <<= 1) {
    int u = (t >= off) ? sm[t - off] : 0;
    __syncthreads();
    sm[t] += u;
    __syncthreads();
  }
  int ex = sm[t] - v;
  gcur[t] = ex;
  bbase[t] = ex;
  if (t == 255) bbase[256] = E;
}

// Phase 1: bucket edges by dst>>8; LDS reorder so global writes are grouped runs.
__global__ __launch_bounds__(256) void k_bucket(const int* __restrict__ ei, int E,
                                                int* __restrict__ gcur,
                                                int2* __restrict__ ebuck) {
  __shared__ int2 stage[EPB];
  __shared__ int cnt[256], offs[256], gbase[256], curl[256], sm[256];
  int t = threadIdx.x;
  int base = blockIdx.x * EPB;
  int count = E - base;
  if (count > EPB) count = EPB;
  if (count < 0) count = 0;
  cnt[t] = 0;
  __syncthreads();
  for (int i = t; i < count; i += 256) {
    int d = ei[E + base + i];
    atomicAdd(&cnt[d >> BSH], 1);
  }
  __syncthreads();
  sm[t] = cnt[t];
  __syncthreads();
#pragma unroll
  for (int off = 1; off < 256; off <<= 1) {
    int u = (t >= off) ? sm[t - off] : 0;
    __syncthreads();
    sm[t] += u;
    __syncthreads();
  }
  offs[t] = sm[t] - cnt[t];
  curl[t] = sm[t] - cnt[t];
  if (cnt[t] > 0) gbase[t] = atomicAdd(&gcur[t], cnt[t]);
  __syncthreads();
  for (int i = t; i < count; i += 256) {
    int s = ei[base + i];
    int d = ei[E + base + i];
    int r = atomicAdd(&curl[d >> BSH], 1);
    stage[r] = make_int2(s, d);
  }
  __syncthreads();
  for (int i = t; i < count; i += 256) {
    int2 e = stage[i];
    int b = e.y >> BSH;
    ebuck[gbase[b] + (i - offs[b])] = e;
  }
}

// Phase 2: per-bucket fine sort; computes rowptr (per-node) in LDS, places edges.
__global__ __launch_bounds__(256) void k_fine(const int2* __restrict__ ebuck,
                                              const int* __restrict__ bbase,
                                              int* __restrict__ rowptr,
                                              int* __restrict__ colx, int n, int E) {
  __shared__ int cnt[256], cur[256], sm[256];
  int b = blockIdx.x, t = threadIdx.x;
  int lo = b << BSH;
  int hi = lo + 256;
  if (hi > n) hi = n;
  int nn = hi - lo;
  int ebeg = bbase[b], eend = bbase[b + 1];
  cnt[t] = 0;
  __syncthreads();
  for (int i = ebeg + t; i < eend; i += 256)
    atomicAdd(&cnt[ebuck[i].y - lo], 1);
  __syncthreads();
  sm[t] = cnt[t];
  __syncthreads();
#pragma unroll
  for (int off = 1; off < 256; off <<= 1) {
    int u = (t >= off) ? sm[t - off] : 0;
    __syncthreads();
    sm[t] += u;
    __syncthreads();
  }
  int nodebase = ebeg + sm[t] - cnt[t];
  if (t < nn) {
    rowptr[lo + t] = nodebase;
    cur[t] = nodebase;
  }
  if (t == 0 && b == gridDim.x - 1) rowptr[n] = E;
  __syncthreads();
  for (int i = ebeg + t; i < eend; i += 256) {
    int2 e = ebuck[i];
    int p = atomicAdd(&cur[e.y - lo], 1);
    colx[p] = e.x;
  }
}

// ---------------- MFMA GEMM + fused attention logits ----------------

__device__ __forceinline__ f16x8 load_a(const float* xp) {
  float4 lo = *(const float4*)xp;
  float4 hi = *(const float4*)(xp + 4);
  f16x8 a;
  a[0] = (_Float16)lo.x; a[1] = (_Float16)lo.y; a[2] = (_Float16)lo.z; a[3] = (_Float16)lo.w;
  a[4] = (_Float16)hi.x; a[5] = (_Float16)hi.y; a[6] = (_Float16)hi.z; a[7] = (_Float16)hi.w;
  return a;
}

__device__ __forceinline__ f16x8 load_a(const __half* xp) {
  return *(const f16x8*)xp;
}

template <int NT, int NH, typename IN, typename OUT>
__global__ __launch_bounds__(256, 2) void gemm_mfma(
    const IN* __restrict__ x, const __half* __restrict__ wfrag,
    const float* __restrict__ a_s, const float* __restrict__ a_d,
    OUT* __restrict__ h, float* __restrict__ als, float* __restrict__ ald,
    int n, int ntiles) {
  int lane = threadIdx.x & 63, w = threadIdx.x >> 6;
  const f16x8* wf = (const f16x8*)wfrag;
  f16x8 B[4][NT];
#pragma unroll
  for (int kt = 0; kt < 4; ++kt)
#pragma unroll
    for (int nt = 0; nt < NT; ++nt) B[kt][nt] = wf[(kt * NT + nt) * 64 + lane];
  int tile = blockIdx.x * 4 + w;
  if (tile >= ntiles) return;
  int r0 = tile * 16;
  int arow = r0 + (lane & 15);
  const IN* xp = x + (size_t)arow * 128 + (lane >> 4) * 8;
  bool full = (r0 + 16 <= n);
  f16x8 A[4];
#pragma unroll
  for (int kt = 0; kt < 4; ++kt) {
    if (full || arow < n) A[kt] = load_a(xp + kt * 32);
    else A[kt] = (f16x8){};
  }
  f32x4 acc[NT];
#pragma unroll
  for (int nt = 0; nt < NT; ++nt) acc[nt] = (f32x4){0.f, 0.f, 0.f, 0.f};
#pragma unroll
  for (int kt = 0; kt < 4; ++kt)
#pragma unroll
    for (int nt = 0; nt < NT; ++nt)
      acc[nt] = __builtin_amdgcn_mfma_f32_16x16x32_f16(A[kt], B[kt][nt], acc[nt], 0, 0, 0);
  int cb = lane & 15, rb = (lane >> 4) * 4;
  float asv[NT], adv[NT];
#pragma unroll
  for (int nt = 0; nt < NT; ++nt) {
    asv[nt] = a_s[nt * 16 + cb];
    adv[nt] = a_d[nt * 16 + cb];
  }
#pragma unroll
  for (int r = 0; r < 4; ++r) {
    int row = r0 + rb + r;
    if (!full && row >= n) break;
#pragma unroll
    for (int nt = 0; nt < NT; ++nt)
      h[(size_t)row * (NT * 16) + nt * 16 + cb] = (OUT)acc[nt][r];
    if (NH == 4) {
      float ps[4], pd[4];
#pragma unroll
      for (int hh = 0; hh < 4; ++hh) {
        ps[hh] = acc[2 * hh][r] * asv[2 * hh] + acc[2 * hh + 1][r] * asv[2 * hh + 1];
        pd[hh] = acc[2 * hh][r] * adv[2 * hh] + acc[2 * hh + 1][r] * adv[2 * hh + 1];
      }
#pragma unroll
      for (int off = 1; off < 16; off <<= 1) {
#pragma unroll
        for (int hh = 0; hh < 4; ++hh) {
          ps[hh] += __shfl_xor(ps[hh], off);
          pd[hh] += __shfl_xor(pd[hh], off);
        }
      }
      if (cb < 4) {
        als[row * 4 + cb] = sel4(ps[0], ps[1], ps[2], ps[3], cb);
        ald[row * 4 + cb] = sel4(pd[0], pd[1], pd[2], pd[3], cb);
      }
    } else {
      float ps = acc[0][r] * asv[0] + acc[1][r] * asv[1];
      float pd = acc[0][r] * adv[0] + acc[1][r] * adv[1];
#pragma unroll
      for (int off = 1; off < 16; off <<= 1) {
        ps += __shfl_xor(ps, off);
        pd += __shfl_xor(pd, off);
      }
      if (cb == 0) { als[row] = ps; ald[row] = pd; }
    }
  }
}

// ---------------- Aggregation, layers 1/2: fused weights, fp16 out ----------------
// lane = (g,q): g=lane>>4 edge group, q=lane&15 owns channels 8q..8q+7 (head=q>>2).

__global__ __launch_bounds__(256) void k_agg128(
    const __half* __restrict__ h, const float* __restrict__ als,
    const float* __restrict__ ald, const int* __restrict__ rowptr,
    const int* __restrict__ colx, const float* __restrict__ bias,
    __half* __restrict__ out, int n) {
  int w = threadIdx.x >> 6, lane = threadIdx.x & 63;
  int node = blockIdx.x * 4 + w;
  if (node >= n) return;
  int g = lane >> 4, q = lane & 15, head = q >> 2;
  int beg = rowptr[node], end = rowptr[node + 1];
  float adh = ald[node * 4 + head];
  float acc[8] = {};
  float z = 0.f;
  if (g == 0) {  // self loop
    float ws = __expf(lrelu(als[node * 4 + head] + adh));
    z = ws;
    float4 raw = *(const float4*)(h + (size_t)node * 128 + q * 8);
    const __half2* hh = (const __half2*)&raw;
#pragma unroll
    for (int j = 0; j < 4; ++j) {
      float2 f = __half22float2(hh[j]);
      acc[2 * j] = ws * f.x;
      acc[2 * j + 1] = ws * f.y;
    }
  }
  for (int e = beg + g; e < end; e += 4) {
    int s = colx[e];
    float wv = __expf(lrelu(als[s * 4 + head] + adh));
    float4 raw = *(const float4*)(h + (size_t)s * 128 + q * 8);
    const __half2* hh = (const __half2*)&raw;
    z += wv;
#pragma unroll
    for (int j = 0; j < 4; ++j) {
      float2 f = __half22float2(hh[j]);
      acc[2 * j] = fmaf(wv, f.x, acc[2 * j]);
      acc[2 * j + 1] = fmaf(wv, f.y, acc[2 * j + 1]);
    }
  }
#pragma unroll
  for (int off = 16; off <= 32; off <<= 1) {
    z += __shfl_xor(z, off);
#pragma unroll
    for (int j = 0; j < 8; ++j) acc[j] += __shfl_xor(acc[j], off);
  }
  if (g == 0) {
    float inv = 1.f / z;
    int c0 = q * 8;
    union { __half h8[8]; float4 v; } u;
#pragma unroll
    for (int j = 0; j < 8; ++j) {
      float v = acc[j] * inv + bias[c0 + j];
      v = (v > 0.f) ? v : (__expf(v) - 1.f);  // elu
      u.h8[j] = (__half)v;
    }
    *(float4*)&out[(size_t)node * 128 + c0] = u.v;
  }
}

// ---------------- Aggregation, layer 3: fp16 gather, fp32 out ----------------

__global__ __launch_bounds__(256) void k_agg32(
    const __half* __restrict__ h, const float* __restrict__ als,
    const float* __restrict__ ald, const int* __restrict__ rowptr,
    const int* __restrict__ colx, const float* __restrict__ bias,
    float* __restrict__ out, int n) {
  int w = threadIdx.x >> 6, lane = threadIdx.x & 63;
  int node = blockIdx.x * 4 + w;
  if (node >= n) return;
  int g = lane >> 4, q = lane & 15;
  int beg = rowptr[node], end = rowptr[node + 1];
  float ad = ald[node];
  float acc0 = 0.f, acc1 = 0.f, z = 0.f;
  if (g == 0) {
    float ws = __expf(lrelu(als[node] + ad));
    float2 f = __half22float2(*(const __half2*)&h[(size_t)node * 32 + 2 * q]);
    z = ws;
    acc0 = ws * f.x;
    acc1 = ws * f.y;
  }
  for (int e = beg + g; e < end; e += 4) {
    int s = colx[e];
    float wv = __expf(lrelu(als[s] + ad));
    float2 f = __half22float2(*(const __half2*)&h[(size_t)s * 32 + 2 * q]);
    z += wv;
    acc0 = fmaf(wv, f.x, acc0);
    acc1 = fmaf(wv, f.y, acc1);
  }
#pragma unroll
  for (int off = 16; off <= 32; off <<= 1) {
    z += __shfl_xor(z, off);
    acc0 += __shfl_xor(acc0, off);
    acc1 += __shfl_xor(acc1, off);
  }
  if (g == 0) {
    float inv = 1.f / z;
    *(float2*)&out[(size_t)node * 32 + 2 * q] =
        make_float2(acc0 * inv + bias[2 * q], acc1 * inv + bias[2 * q + 1]);
  }
}

// ---------------- launch ----------------

extern "C" void kernel_launch(void* const* d_in, const int* in_sizes, int n_in,
                              void* d_out, int out_size, void* d_ws, size_t ws_size,
                              hipStream_t stream) {
  const float* x   = (const float*)d_in[0];
  const int*   ei  = (const int*)d_in[1];
  const float* W1  = (const float*)d_in[4];
  const float* a1s = (const float*)d_in[5];
  const float* a1d = (const float*)d_in[6];
  const float* b1  = (const float*)d_in[7];
  const float* W2  = (const float*)d_in[8];
  const float* a2s = (const float*)d_in[9];
  const float* a2d = (const float*)d_in[10];
  const float* b2  = (const float*)d_in[11];
  const float* W3  = (const float*)d_in[12];
  const float* a3s = (const float*)d_in[13];
  const float* a3d = (const float*)d_in[14];
  const float* b3  = (const float*)d_in[15];
  const int N = in_sizes[0] / 128;
  const int E = in_sizes[1] / 2;
  const int ntiles = (N + 15) / 16;
  const int nbuck = (N + 255) >> BSH;

  char* ws = (char*)d_ws;
  size_t off = 0;
  auto alloc = [&](size_t bytes) -> void* {
    void* p = ws + off;
    off += (bytes + 255) & ~(size_t)255;
    return p;
  };
  __half* hA    = (__half*)alloc((size_t)N * 128 * 2);  // gemm out (pre-agg features)
  __half* hB    = (__half*)alloc((size_t)N * 128 * 2);  // agg out (next-layer input)
  __half* h32   = (__half*)alloc((size_t)N * 32 * 2);   // layer-3 features
  float*  als   = (float*)alloc((size_t)N * 4 * 4);
  float*  ald   = (float*)alloc((size_t)N * 4 * 4);
  float*  als1  = (float*)alloc((size_t)N * 4);
  float*  ald1  = (float*)alloc((size_t)N * 4);
  int* rowptr   = (int*)alloc((size_t)(N + 1) * 4);
  int* bcnt     = (int*)alloc(256 * 4);
  int* gcur     = (int*)alloc(256 * 4);
  int* bbase    = (int*)alloc(257 * 4);
  int2* ebuck   = (int2*)alloc((size_t)E * 8);
  int* colx     = (int*)alloc((size_t)E * 4);
  __half* wf1   = (__half*)alloc(4 * 8 * 64 * 8 * 2);
  __half* wf2   = (__half*)alloc(4 * 8 * 64 * 8 * 2);
  __half* wf3   = (__half*)alloc(4 * 2 * 64 * 8 * 2);
  (void)ws_size; (void)n_in; (void)out_size;

  // CSR build (bucket-level counts only; per-node rowptr computed in k_fine)
  k_zero<<<1, 256, 0, stream>>>(bcnt);
  int cntBlocks = (E / 4 + 255) / 256;
  k_bcnt<<<cntBlocks + 18, 256, 0, stream>>>(ei + E, E, bcnt, cntBlocks,
                                             W1, wf1, W2, wf2, W3, wf3);
  k_bscan<<<1, 256, 0, stream>>>(bcnt, gcur, bbase, E);
  k_bucket<<<(E + EPB - 1) / EPB, 256, 0, stream>>>(ei, E, gcur, ebuck);
  k_fine<<<nbuck, 256, 0, stream>>>(ebuck, bbase, rowptr, colx, N, E);

  int gblk = (ntiles + 3) / 4;
  // Layer 1 (fp32 input)
  gemm_mfma<8, 4, float, __half><<<gblk, 256, 0, stream>>>(x, wf1, a1s, a1d, hA, als, ald, N, ntiles);
  k_agg128<<<(N + 3) / 4, 256, 0, stream>>>(hA, als, ald, rowptr, colx, b1, hB, N);
  // Layer 2 (fp16 input)
  gemm_mfma<8, 4, __half, __half><<<gblk, 256, 0, stream>>>(hB, wf2, a2s, a2d, hA, als, ald, N, ntiles);
  k_agg128<<<(N + 3) / 4, 256, 0, stream>>>(hA, als, ald, rowptr, colx, b2, hB, N);
  // Layer 3 (fp16 input, fp16 h, fp32 final out)
  gemm_mfma<2, 1, __half, __half><<<gblk, 256, 0, stream>>>(hB, wf3, a3s, a3d, h32, als1, ald1, N, ntiles);
  k_agg32<<<(N + 3) / 4, 256, 0, stream>>>(h32, als1, ald1, rowptr, colx, b3, (float*)d_out, N);
}